// Round 6
// baseline (3999.511 us; speedup 1.0000x reference)
//
#include <hip/hip_runtime.h>

// Recurrent MLP emulator: B=65536 rows, T=256 steps, MLP 18->32->32->14.
// One thread per row, state in registers. Weights staged once into LDS
// (race-free), then re-read EVERY step as uniform-address ds_read_b128
// broadcasts (in-order lgkmcnt -> deep compiler pipelining into the ~450
// free VGPRs at 1 wave/SIMD). asm memory clobber per iteration stops LICM
// from hoisting 8.6KB of loop-invariant LDS reads into registers.

#define BB 65536
#define TT 256
#define PP 4
#define LL 14
#define HH 32
#define INW 18

// LDS layout in floats (all 16B-aligned regions)
#define OW1 0        // W1: 18 x 32 = 576
#define OW2 576      // W2: 32 x 32 = 1024
#define OW3 1600     // W3: 32 rows x 16 (14 data + 2 zero pad) = 512
#define OB1 2112     // b1: 32
#define OB2 2144     // b2: 32
#define OB3 2176     // b3: 14 + 2 pad = 16
#define WTOT 2192    // 8768 bytes

__global__ __launch_bounds__(256, 1)
void emulator_kernel(const float* __restrict__ phys,
                     const float* __restrict__ latents,
                     const float* __restrict__ W1,
                     const float* __restrict__ b1,
                     const float* __restrict__ W2,
                     const float* __restrict__ b2,
                     const float* __restrict__ W3,
                     const float* __restrict__ b3,
                     float* __restrict__ out) {
    __shared__ __align__(16) float wbuf[WTOT];
    const int tid = threadIdx.x;

    // ---- stage weights into LDS; every cell written exactly once ----
    for (int i = tid; i < 576; i += 256)  wbuf[OW1 + i] = W1[i];
    for (int i = tid; i < 1024; i += 256) wbuf[OW2 + i] = W2[i];
    for (int i = tid; i < 512; i += 256) {
        const int k = i >> 4, l = i & 15;
        wbuf[OW3 + i] = (l < LL) ? W3[k * LL + l] : 0.0f;
    }
    if (tid < 32)                 wbuf[OB1 + tid] = b1[tid];
    if (tid >= 32 && tid < 64)    wbuf[OB2 + (tid - 32)] = b2[tid - 32];
    if (tid >= 64 && tid < 80) {
        const int l = tid - 64;
        wbuf[OB3 + l] = (l < LL) ? b3[l] : 0.0f;
    }
    __syncthreads();

    const int b = blockIdx.x * blockDim.x + tid;

    // Latent state in registers.
    float lat[LL];
    {
        const float2* l2 = reinterpret_cast<const float2*>(latents + (size_t)b * LL);
#pragma unroll
        for (int i = 0; i < LL / 2; ++i) {
            const float2 v = l2[i];
            lat[2 * i] = v.x;
            lat[2 * i + 1] = v.y;
        }
    }

    // phys[b][t][0:4] is a 16B-aligned float4 per (b,t).
    const float4* __restrict__ physv =
        reinterpret_cast<const float4*>(phys + (size_t)b * TT * PP);
    float4 ph = physv[0];

    float* __restrict__ outp = out + (size_t)b * TT * LL;

    const float4* wq = reinterpret_cast<const float4*>(wbuf);  // quad view

#pragma unroll 1
    for (int t = 0; t < TT; ++t) {
        // Stop cross-iteration caching/hoisting of LDS weight reads; keeps
        // addresses compile-time constant (ds_read_b128 base + offset:N).
        asm volatile("" ::: "memory");

        const float4 ph_next = physv[(t < TT - 1) ? (t + 1) : t];

        float x[INW];
        x[0] = ph.x; x[1] = ph.y; x[2] = ph.z; x[3] = ph.w;
#pragma unroll
        for (int i = 0; i < LL; ++i) x[PP + i] = lat[i];

        // ---- layer 1: h1 = relu(b1 + x @ W1) ----
        float h1[HH];
#pragma unroll
        for (int g = 0; g < HH / 4; ++g) {
            const float4 q = wq[OB1 / 4 + g];
            h1[4 * g + 0] = q.x; h1[4 * g + 1] = q.y;
            h1[4 * g + 2] = q.z; h1[4 * g + 3] = q.w;
        }
#pragma unroll
        for (int i = 0; i < INW; ++i) {
            const float xi = x[i];
#pragma unroll
            for (int g = 0; g < HH / 4; ++g) {
                const float4 q = wq[OW1 / 4 + i * 8 + g];
                h1[4 * g + 0] = fmaf(xi, q.x, h1[4 * g + 0]);
                h1[4 * g + 1] = fmaf(xi, q.y, h1[4 * g + 1]);
                h1[4 * g + 2] = fmaf(xi, q.z, h1[4 * g + 2]);
                h1[4 * g + 3] = fmaf(xi, q.w, h1[4 * g + 3]);
            }
        }
#pragma unroll
        for (int j = 0; j < HH; ++j) h1[j] = fmaxf(h1[j], 0.0f);

        // ---- layer 2: h2 = relu(b2 + h1 @ W2) ----
        float h2[HH];
#pragma unroll
        for (int g = 0; g < HH / 4; ++g) {
            const float4 q = wq[OB2 / 4 + g];
            h2[4 * g + 0] = q.x; h2[4 * g + 1] = q.y;
            h2[4 * g + 2] = q.z; h2[4 * g + 3] = q.w;
        }
#pragma unroll
        for (int k = 0; k < HH; ++k) {
            const float hk = h1[k];
#pragma unroll
            for (int g = 0; g < HH / 4; ++g) {
                const float4 q = wq[OW2 / 4 + k * 8 + g];
                h2[4 * g + 0] = fmaf(hk, q.x, h2[4 * g + 0]);
                h2[4 * g + 1] = fmaf(hk, q.y, h2[4 * g + 1]);
                h2[4 * g + 2] = fmaf(hk, q.z, h2[4 * g + 2]);
                h2[4 * g + 3] = fmaf(hk, q.w, h2[4 * g + 3]);
            }
        }
#pragma unroll
        for (int j = 0; j < HH; ++j) h2[j] = fmaxf(h2[j], 0.0f);

        // ---- layer 3 + residual: lat += b3 + h2 @ W3 (rows padded to 16) ----
        {
            const float4 c0 = wq[OB3 / 4 + 0];
            const float4 c1 = wq[OB3 / 4 + 1];
            const float4 c2 = wq[OB3 / 4 + 2];
            const float4 c3 = wq[OB3 / 4 + 3];
            lat[0] += c0.x; lat[1] += c0.y; lat[2]  += c0.z; lat[3]  += c0.w;
            lat[4] += c1.x; lat[5] += c1.y; lat[6]  += c1.z; lat[7]  += c1.w;
            lat[8] += c2.x; lat[9] += c2.y; lat[10] += c2.z; lat[11] += c2.w;
            lat[12] += c3.x; lat[13] += c3.y;
        }
#pragma unroll
        for (int k = 0; k < HH; ++k) {
            const float hk = h2[k];
            const float4 q0 = wq[OW3 / 4 + k * 4 + 0];
            const float4 q1 = wq[OW3 / 4 + k * 4 + 1];
            const float4 q2 = wq[OW3 / 4 + k * 4 + 2];
            const float4 q3 = wq[OW3 / 4 + k * 4 + 3];
            lat[0]  = fmaf(hk, q0.x, lat[0]);
            lat[1]  = fmaf(hk, q0.y, lat[1]);
            lat[2]  = fmaf(hk, q0.z, lat[2]);
            lat[3]  = fmaf(hk, q0.w, lat[3]);
            lat[4]  = fmaf(hk, q1.x, lat[4]);
            lat[5]  = fmaf(hk, q1.y, lat[5]);
            lat[6]  = fmaf(hk, q1.z, lat[6]);
            lat[7]  = fmaf(hk, q1.w, lat[7]);
            lat[8]  = fmaf(hk, q2.x, lat[8]);
            lat[9]  = fmaf(hk, q2.y, lat[9]);
            lat[10] = fmaf(hk, q2.z, lat[10]);
            lat[11] = fmaf(hk, q2.w, lat[11]);
            lat[12] = fmaf(hk, q3.x, lat[12]);
            lat[13] = fmaf(hk, q3.y, lat[13]);
        }

        // ---- store out[b][t][:]: 14 floats, 8B-aligned -> 7 x float2 ----
        float2* __restrict__ o2 = reinterpret_cast<float2*>(outp + t * LL);
#pragma unroll
        for (int l = 0; l < LL / 2; ++l)
            o2[l] = make_float2(lat[2 * l], lat[2 * l + 1]);

        ph = ph_next;
    }
}

extern "C" void kernel_launch(void* const* d_in, const int* in_sizes, int n_in,
                              void* d_out, int out_size, void* d_ws, size_t ws_size,
                              hipStream_t stream) {
    const float* phys    = (const float*)d_in[0];
    const float* latents = (const float*)d_in[1];
    const float* W1      = (const float*)d_in[2];
    const float* b1      = (const float*)d_in[3];
    const float* W2      = (const float*)d_in[4];
    const float* b2      = (const float*)d_in[5];
    const float* W3      = (const float*)d_in[6];
    const float* b3      = (const float*)d_in[7];
    float* out = (float*)d_out;

    const int threads = 256;
    const int blocks = BB / threads;  // 256 blocks, 1 per CU
    emulator_kernel<<<blocks, threads, 0, stream>>>(
        phys, latents, W1, b1, W2, b2, W3, b3, out);
}

// Round 8
// 2806.743 us; speedup vs baseline: 1.4250x; 1.4250x over previous
//
#include <hip/hip_runtime.h>

// Recurrent MLP emulator: B=65536 rows, T=256 steps, MLP 18->32->32->14.
// One thread per row. Weight delivery analysis (R1..R6):
//   - VMEM/LDS delivery pays 64x per-lane replication -> dead ends
//     (R1=3.0ms, R6=4.0ms).
//   - SMEM (s_load -> SGPR, v_fmac v,s,v) is replication-free. R4=1.9ms,
//     limited by lgkmcnt(0) drains (SMEM returns out-of-order).
// This round: (a) pin 302 weights (W3 rows 0..15 + all biases) in VGPRs for
// the whole t-loop (loaded once via VMEM float4 from generic pointers);
// (b) stream W1/W2/rest-of-W3 through SGPRs with scalar AS4 loads (compiler
// merges contiguous s_loads to dwordx16) in whole-row blocks -> fewer,
// larger lgkmcnt drains per step.
// NOTE: address_space(4) float4 copy-ctor doesn't compile (HIP_vector_type
// ctor can't bind AS4 reference) -> stream with SCALAR AS4 loads only.

#define BB 65536
#define TT 256
#define PP 4
#define LL 14
#define HH 32
#define INW 18

typedef const __attribute__((address_space(4))) float* cfp;

__global__ __launch_bounds__(256, 1)
void emulator_kernel(const float* __restrict__ phys,
                     const float* __restrict__ latents,
                     const float* __restrict__ W1g,
                     const float* __restrict__ b1g,
                     const float* __restrict__ W2g,
                     const float* __restrict__ b2g,
                     const float* __restrict__ W3g,
                     const float* __restrict__ b3g,
                     float* __restrict__ out) {
    const int tid = threadIdx.x;
    const int b = blockIdx.x * blockDim.x + tid;

    // ---- pinned weights: loaded ONCE via VMEM (live in VGPRs across t) ----
    // W3 rows 0..15 = floats 0..223 = 56 float4 quads (W3g is 16B-aligned).
    float4 pw3[56];
    {
        const float4* w3q = reinterpret_cast<const float4*>(W3g);
#pragma unroll
        for (int q = 0; q < 56; ++q) pw3[q] = w3q[q];
    }
    float4 pb1[8], pb2[8];
    {
        const float4* q1 = reinterpret_cast<const float4*>(b1g);
        const float4* q2 = reinterpret_cast<const float4*>(b2g);
#pragma unroll
        for (int g = 0; g < 8; ++g) { pb1[g] = q1[g]; pb2[g] = q2[g]; }
    }
    float pb3[LL];
#pragma unroll
    for (int l = 0; l < LL; ++l) pb3[l] = b3g[l];

    // ---- streamed weight bases (mangled per-iteration against LICM) ----
    unsigned long long aW1 = (unsigned long long)W1g;
    unsigned long long aW2 = (unsigned long long)W2g;
    unsigned long long aW3s = (unsigned long long)(W3g + 224);  // rows 16..31

    // ---- per-row state ----
    float lat[LL];
    {
        const float2* l2 = reinterpret_cast<const float2*>(latents + (size_t)b * LL);
#pragma unroll
        for (int i = 0; i < LL / 2; ++i) {
            const float2 v = l2[i];
            lat[2 * i] = v.x;
            lat[2 * i + 1] = v.y;
        }
    }

    const float4* __restrict__ physv =
        reinterpret_cast<const float4*>(phys + (size_t)b * TT * PP);
    float4 ph = physv[0];

    float* __restrict__ outp = out + (size_t)b * TT * LL;

#pragma unroll 1
    for (int t = 0; t < TT; ++t) {
        // Anti-LICM on streamed bases only; pinned VGPR values unaffected.
        asm volatile("" : "+s"(aW1), "+s"(aW2), "+s"(aW3s));
        cfp cw1 = (cfp)aW1;   // W1: 18 rows x 32
        cfp cw2 = (cfp)aW2;   // W2: 32 rows x 32
        cfp cw3 = (cfp)aW3s;  // W3 rows 16..31: 224 floats

        const float4 ph_next = physv[(t < TT - 1) ? (t + 1) : t];

        // x = [ph, lat]
        float x[INW];
        x[0] = ph.x; x[1] = ph.y; x[2] = ph.z; x[3] = ph.w;
#pragma unroll
        for (int i = 0; i < LL; ++i) x[PP + i] = lat[i];

        // ---- layer 1: h1 = relu(pinned_b1 + x @ W1_streamed) ----
        float h1[HH];
#pragma unroll
        for (int g = 0; g < 8; ++g) {
            h1[4 * g + 0] = pb1[g].x; h1[4 * g + 1] = pb1[g].y;
            h1[4 * g + 2] = pb1[g].z; h1[4 * g + 3] = pb1[g].w;
        }
#pragma unroll
        for (int i = 0; i < INW; ++i) {
            const float xi = x[i];
#pragma unroll
            for (int j = 0; j < HH; ++j)
                h1[j] = fmaf(xi, cw1[i * HH + j], h1[j]);  // merged s_loads
        }
#pragma unroll
        for (int j = 0; j < HH; ++j) h1[j] = fmaxf(h1[j], 0.0f);

        // ---- layer 2: h2 = relu(pinned_b2 + h1 @ W2_streamed) ----
        float h2[HH];
#pragma unroll
        for (int g = 0; g < 8; ++g) {
            h2[4 * g + 0] = pb2[g].x; h2[4 * g + 1] = pb2[g].y;
            h2[4 * g + 2] = pb2[g].z; h2[4 * g + 3] = pb2[g].w;
        }
#pragma unroll
        for (int k = 0; k < HH; ++k) {
            const float hk = h1[k];
#pragma unroll
            for (int j = 0; j < HH; ++j)
                h2[j] = fmaf(hk, cw2[k * HH + j], h2[j]);
        }
#pragma unroll
        for (int j = 0; j < HH; ++j) h2[j] = fmaxf(h2[j], 0.0f);

        // ---- layer 3 + residual ----
#pragma unroll
        for (int l = 0; l < LL; ++l) lat[l] += pb3[l];
        // rows 0..15 from pinned VGPR quads (flat index n = k*14 + l)
#pragma unroll
        for (int q = 0; q < 56; ++q) {
            const float4 v = pw3[q];
            const int n = 4 * q;
            lat[(n + 0) % LL] = fmaf(h2[(n + 0) / LL], v.x, lat[(n + 0) % LL]);
            lat[(n + 1) % LL] = fmaf(h2[(n + 1) / LL], v.y, lat[(n + 1) % LL]);
            lat[(n + 2) % LL] = fmaf(h2[(n + 2) / LL], v.z, lat[(n + 2) % LL]);
            lat[(n + 3) % LL] = fmaf(h2[(n + 3) / LL], v.w, lat[(n + 3) % LL]);
        }
        // rows 16..31 streamed through SGPRs (flat n = 224 + 4q over W3,
        // i.e. cw3 local index 4q)
#pragma unroll
        for (int q = 0; q < 56; ++q) {
            const int n = 224 + 4 * q;
            lat[(n + 0) % LL] = fmaf(h2[(n + 0) / LL], cw3[4 * q + 0], lat[(n + 0) % LL]);
            lat[(n + 1) % LL] = fmaf(h2[(n + 1) / LL], cw3[4 * q + 1], lat[(n + 1) % LL]);
            lat[(n + 2) % LL] = fmaf(h2[(n + 2) / LL], cw3[4 * q + 2], lat[(n + 2) % LL]);
            lat[(n + 3) % LL] = fmaf(h2[(n + 3) / LL], cw3[4 * q + 3], lat[(n + 3) % LL]);
        }

        // ---- store out[b][t][:]: 14 floats -> 7 x float2 ----
        float2* __restrict__ o2 = reinterpret_cast<float2*>(outp + t * LL);
#pragma unroll
        for (int l = 0; l < LL / 2; ++l)
            o2[l] = make_float2(lat[2 * l], lat[2 * l + 1]);

        ph = ph_next;
    }
}

extern "C" void kernel_launch(void* const* d_in, const int* in_sizes, int n_in,
                              void* d_out, int out_size, void* d_ws, size_t ws_size,
                              hipStream_t stream) {
    const float* phys    = (const float*)d_in[0];
    const float* latents = (const float*)d_in[1];
    const float* W1      = (const float*)d_in[2];
    const float* b1      = (const float*)d_in[3];
    const float* W2      = (const float*)d_in[4];
    const float* b2      = (const float*)d_in[5];
    const float* W3      = (const float*)d_in[6];
    const float* b3      = (const float*)d_in[7];
    float* out = (float*)d_out;

    const int threads = 256;
    const int blocks = BB / threads;  // 256 blocks, 1 per CU
    emulator_kernel<<<blocks, threads, 0, stream>>>(
        phys, latents, W1, b1, W2, b2, W3, b3, out);
}

// Round 10
// 672.458 us; speedup vs baseline: 5.9476x; 4.1739x over previous
//
#include <hip/hip_runtime.h>

// Recurrent MLP emulator: B=65536 rows, T=256 steps, MLP 18->32->32->14.
// MFMA rewrite: one wave per 16 batch rows, split-bf16 fp32 emulation
// (hi/lo, 3 MFMAs per tile, fp32 accumulate). Transposed orientation:
//   h^T = W^T @ x^T  via mfma_f32_16x16x32_bf16(A=W^T tile, B=x^T)
// so the batch index stays lane-local (col = lane&15) through all layers
// and across steps. W^T tiles are pinned in VGPRs as bf16 hi/lo fragments
// (~60 VGPR); layer boundaries regroup h between lane g-groups with
// ds_bpermute. 4096 waves = 4/SIMD -> latency hiding. No LDS, no barriers,
// no per-step weight traffic.
// (Resubmission of R9 — container infra failure, kernel never ran.)

#define BB 65536
#define TT 256
#define LL 14
#define HH 32

typedef float f32x4 __attribute__((ext_vector_type(4)));
typedef __bf16 bf16x8 __attribute__((ext_vector_type(8)));

static __device__ __forceinline__ unsigned bp(int idx, unsigned v) {
    return (unsigned)__builtin_amdgcn_ds_bpermute(idx, (int)v);
}

// Split two fp32 into packed bf16 hi-word and lo-word (RTN via +0x8000).
// hi = bf16(v); lo = bf16(v - hi). Effective input precision ~2^-17 rel.
static __device__ __forceinline__ void split2(float v0, float v1,
                                              unsigned& hw, unsigned& lw) {
    unsigned u0 = __float_as_uint(v0), u1 = __float_as_uint(v1);
    unsigned h0 = (u0 + 0x8000u) & 0xFFFF0000u;
    unsigned h1 = (u1 + 0x8000u) & 0xFFFF0000u;
    float l0 = v0 - __uint_as_float(h0);
    float l1 = v1 - __uint_as_float(h1);
    unsigned s0 = __float_as_uint(l0), s1 = __float_as_uint(l1);
    hw = (h0 >> 16) | h1;
    lw = ((s0 + 0x8000u) >> 16) | ((s1 + 0x8000u) & 0xFFFF0000u);
}

static __device__ __forceinline__ bf16x8 mkfrag(unsigned w0, unsigned w1,
                                                unsigned w2, unsigned w3) {
    union { unsigned u[4]; bf16x8 v; } x;
    x.u[0] = w0; x.u[1] = w1; x.u[2] = w2; x.u[3] = w3;
    return x.v;
}

static __device__ __forceinline__ f32x4 mf(bf16x8 a, bf16x8 b, f32x4 c) {
    return __builtin_amdgcn_mfma_f32_16x16x32_bf16(a, b, c, 0, 0, 0);
}

// Regroup h (two D-tiles: a0 = h[4g+i], a1 = h[16+4g+i], batch col c)
// into the B-fragment for the next MFMA (slot j <-> k = 8g+j).
static __device__ __forceinline__ void h2frag(f32x4 a0, f32x4 a1, bool lo2,
                                              int idxE, int idxO,
                                              bf16x8& Bh, bf16x8& Bl) {
    unsigned A0h, A0l, A1h, A1l, C0h, C0l, C1h, C1l;
    split2(a0[0], a0[1], A0h, A0l);
    split2(a0[2], a0[3], A1h, A1l);
    split2(a1[0], a1[1], C0h, C0l);
    split2(a1[2], a1[3], C1h, C1l);
    unsigned e, f;
    e = bp(idxE, A0h); f = bp(idxE, C0h); unsigned P0h = lo2 ? e : f;
    e = bp(idxE, A0l); f = bp(idxE, C0l); unsigned P0l = lo2 ? e : f;
    e = bp(idxE, A1h); f = bp(idxE, C1h); unsigned P1h = lo2 ? e : f;
    e = bp(idxE, A1l); f = bp(idxE, C1l); unsigned P1l = lo2 ? e : f;
    e = bp(idxO, A0h); f = bp(idxO, C0h); unsigned P2h = lo2 ? e : f;
    e = bp(idxO, A0l); f = bp(idxO, C0l); unsigned P2l = lo2 ? e : f;
    e = bp(idxO, A1h); f = bp(idxO, C1h); unsigned P3h = lo2 ? e : f;
    e = bp(idxO, A1l); f = bp(idxO, C1l); unsigned P3l = lo2 ? e : f;
    Bh = mkfrag(P0h, P1h, P2h, P3h);
    Bl = mkfrag(P0l, P1l, P2l, P3l);
}

__global__ __launch_bounds__(256, 4)
void emulator_kernel(const float* __restrict__ phys,
                     const float* __restrict__ latents,
                     const float* __restrict__ W1g,
                     const float* __restrict__ b1g,
                     const float* __restrict__ W2g,
                     const float* __restrict__ b2g,
                     const float* __restrict__ W3g,
                     const float* __restrict__ b3g,
                     float* __restrict__ out) {
    const int tid = threadIdx.x;
    const int lane = tid & 63;
    const int wv = tid >> 6;
    const int c = lane & 15;       // batch column within wave's 16 rows
    const int g = lane >> 4;       // lane group 0..3
    const int row_base = blockIdx.x * 64 + wv * 16;
    const int r = row_base + c;

    // ds_bpermute byte indices (precomputed lane maps)
    const int idxE = (32 * (g & 1) + c) << 2;
    const int idxO = idxE + 64;
    const int idxL = (16 + 32 * (g >> 1) + c) << 2;

    // ---- pinned weight fragments: A-layout m = lane&15, k-slot = (g, j) ----
    bf16x8 w1h[2], w1l[2], w2h[2], w2l[2], w3h, w3l;
#pragma unroll
    for (int tau = 0; tau < 2; ++tau) {
        unsigned hw[4], lw[4];
#pragma unroll
        for (int w = 0; w < 4; ++w) {
            const int k0 = 8 * g + 2 * w, k1 = k0 + 1;
            const float e0 = (k0 < 18) ? W1g[k0 * HH + 16 * tau + c] : 0.0f;
            const float e1 = (k1 < 18) ? W1g[k1 * HH + 16 * tau + c] : 0.0f;
            split2(e0, e1, hw[w], lw[w]);
        }
        w1h[tau] = mkfrag(hw[0], hw[1], hw[2], hw[3]);
        w1l[tau] = mkfrag(lw[0], lw[1], lw[2], lw[3]);
    }
#pragma unroll
    for (int tau = 0; tau < 2; ++tau) {
        unsigned hw[4], lw[4];
#pragma unroll
        for (int w = 0; w < 4; ++w) {
            const int k0 = 8 * g + 2 * w;
            const float e0 = W2g[k0 * HH + 16 * tau + c];
            const float e1 = W2g[(k0 + 1) * HH + 16 * tau + c];
            split2(e0, e1, hw[w], lw[w]);
        }
        w2h[tau] = mkfrag(hw[0], hw[1], hw[2], hw[3]);
        w2l[tau] = mkfrag(lw[0], lw[1], lw[2], lw[3]);
    }
    {
        unsigned hw[4], lw[4];
#pragma unroll
        for (int w = 0; w < 4; ++w) {
            const int k0 = 8 * g + 2 * w;
            const float e0 = (c < LL) ? W3g[k0 * LL + c] : 0.0f;
            const float e1 = (c < LL) ? W3g[(k0 + 1) * LL + c] : 0.0f;
            split2(e0, e1, hw[w], lw[w]);
        }
        w3h = mkfrag(hw[0], hw[1], hw[2], hw[3]);
        w3l = mkfrag(lw[0], lw[1], lw[2], lw[3]);
    }

    // ---- bias C-init fragments (D-layout: row = 4g+i, col = c) ----
    f32x4 cb1[2], cb2[2], cb3;
#pragma unroll
    for (int tau = 0; tau < 2; ++tau)
#pragma unroll
        for (int i = 0; i < 4; ++i) {
            cb1[tau][i] = b1g[16 * tau + 4 * g + i];
            cb2[tau][i] = b2g[16 * tau + 4 * g + i];
        }
#pragma unroll
    for (int i = 0; i < 4; ++i) {
        const int l = 4 * g + i;
        cb3[i] = (l < LL) ? b3g[l] : 0.0f;
    }

    // ---- latent state: lane holds lat[4g .. 4g+3] for batch col c ----
    f32x4 lat;
    {
        const float2* lp = reinterpret_cast<const float2*>(
            latents + (size_t)r * LL + 4 * g);
        const float2 v01 = lp[0];
        lat[0] = v01.x; lat[1] = v01.y;
        if (g < 3) {
            const float2 v23 = lp[1];
            lat[2] = v23.x; lat[3] = v23.y;
        } else {
            lat[2] = 0.0f; lat[3] = 0.0f;
        }
    }

    const float4* pv = reinterpret_cast<const float4*>(phys) + (size_t)r * TT;
    float4 ph = pv[0];

    float* outr = out + ((size_t)r * TT) * LL + 4 * g;

#pragma unroll 1
    for (int t = 0; t < TT; ++t) {
        const float4 phn = pv[(t < TT - 1) ? (t + 1) : t];

        // ---- build B-frag for L1 from [phys, lat] (k = in-dim) ----
        unsigned LP0h, LP0l, LP1h, LP1l, PH0h, PH0l, PH1h, PH1l;
        split2(lat[0], lat[1], LP0h, LP0l);
        split2(lat[2], lat[3], LP1h, LP1l);
        split2(ph.x, ph.y, PH0h, PH0l);
        split2(ph.z, ph.w, PH1h, PH1l);
        unsigned P0h = bp(idxL, LP0h), P0l = bp(idxL, LP0l);
        unsigned P1h = bp(idxL, LP1h), P1l = bp(idxL, LP1l);
        unsigned P2h = bp(idxE, LP0h), P2l = bp(idxE, LP0l);
        unsigned P3h = bp(idxE, LP1h), P3l = bp(idxE, LP1l);
        if (g == 0) { P0h = PH0h; P0l = PH0l; P1h = PH1h; P1l = PH1l; }
        bf16x8 Bh = mkfrag(P0h, P1h, P2h, P3h);
        bf16x8 Bl = mkfrag(P0l, P1l, P2l, P3l);

        // ---- L1: h1^T = W1^T x^T + b1 (2 tiles x 3 split-MFMAs) ----
        f32x4 a0 = mf(w1l[0], Bh, mf(w1h[0], Bl, mf(w1h[0], Bh, cb1[0])));
        f32x4 a1 = mf(w1l[1], Bh, mf(w1h[1], Bl, mf(w1h[1], Bh, cb1[1])));
#pragma unroll
        for (int i = 0; i < 4; ++i) {
            a0[i] = fmaxf(a0[i], 0.0f);
            a1[i] = fmaxf(a1[i], 0.0f);
        }

        // ---- regroup h1 -> B-frag; L2 ----
        h2frag(a0, a1, g < 2, idxE, idxO, Bh, Bl);
        f32x4 d0 = mf(w2l[0], Bh, mf(w2h[0], Bl, mf(w2h[0], Bh, cb2[0])));
        f32x4 d1 = mf(w2l[1], Bh, mf(w2h[1], Bl, mf(w2h[1], Bh, cb2[1])));
#pragma unroll
        for (int i = 0; i < 4; ++i) {
            d0[i] = fmaxf(d0[i], 0.0f);
            d1[i] = fmaxf(d1[i], 0.0f);
        }

        // ---- regroup h2 -> B-frag; L3 + residual ----
        h2frag(d0, d1, g < 2, idxE, idxO, Bh, Bl);
        f32x4 dl = mf(w3l, Bh, mf(w3h, Bl, mf(w3h, Bh, cb3)));
#pragma unroll
        for (int i = 0; i < 4; ++i) lat[i] += dl[i];

        // ---- store out[r][t][4g .. 4g+3] (lat dims 14,15 are zero pad) ----
        float* ob = outr + t * LL;
        *reinterpret_cast<float2*>(ob) = make_float2(lat[0], lat[1]);
        if (g < 3)
            *reinterpret_cast<float2*>(ob + 2) = make_float2(lat[2], lat[3]);

        ph = phn;
    }
}

extern "C" void kernel_launch(void* const* d_in, const int* in_sizes, int n_in,
                              void* d_out, int out_size, void* d_ws, size_t ws_size,
                              hipStream_t stream) {
    const float* phys    = (const float*)d_in[0];
    const float* latents = (const float*)d_in[1];
    const float* W1      = (const float*)d_in[2];
    const float* b1      = (const float*)d_in[3];
    const float* W2      = (const float*)d_in[4];
    const float* b2      = (const float*)d_in[5];
    const float* W3      = (const float*)d_in[6];
    const float* b3      = (const float*)d_in[7];
    float* out = (float*)d_out;

    const int threads = 256;                 // 4 waves x 16 rows = 64 rows/block
    const int blocks = BB / 64;              // 1024 blocks -> 4 waves/SIMD
    emulator_kernel<<<blocks, threads, 0, stream>>>(
        phys, latents, W1, b1, W2, b2, W3, b3, out);
}

// Round 11
// 666.796 us; speedup vs baseline: 5.9981x; 1.0085x over previous
//
#include <hip/hip_runtime.h>

// Recurrent MLP emulator: B=65536 rows, T=256 steps, MLP 18->32->32->14.
// 32x32x16 MFMA design: one wave = 32 batch rows; h (32-dim) fits ONE tile.
// Split-bf16 fp32 emulation (hi/lo, 3 MFMAs per K-tile, fp32 accumulate).
// All cross-lane regrouping is lane <-> lane+32 (permlane32_swap, VALU pipe)
// -> zero DS-pipe traffic (R10's 7.5e7 LDS bank conflicts from ds_bpermute).
// Weights pinned in VGPRs as bf16 hi/lo A-frags; residual folded into L3's
// C operand. 2048 waves = 2/SIMD.

#define BB 65536
#define TT 256
#define LL 14
#define HH 32

typedef float f32x16 __attribute__((ext_vector_type(16)));
typedef __bf16 bf16x8 __attribute__((ext_vector_type(8)));
typedef int i32x2 __attribute__((ext_vector_type(2)));

static __device__ __forceinline__ void split2(float v0, float v1,
                                              unsigned& hw, unsigned& lw) {
    unsigned u0 = __float_as_uint(v0), u1 = __float_as_uint(v1);
    unsigned h0 = (u0 + 0x8000u) & 0xFFFF0000u;
    unsigned h1 = (u1 + 0x8000u) & 0xFFFF0000u;
    float l0 = v0 - __uint_as_float(h0);
    float l1 = v1 - __uint_as_float(h1);
    unsigned s0 = __float_as_uint(l0), s1 = __float_as_uint(l1);
    hw = (h0 >> 16) | h1;
    lw = ((s0 + 0x8000u) >> 16) | ((s1 + 0x8000u) & 0xFFFF0000u);
}

static __device__ __forceinline__ bf16x8 mkfrag(unsigned w0, unsigned w1,
                                                unsigned w2, unsigned w3) {
    union { unsigned u[4]; bf16x8 v; } x;
    x.u[0] = w0; x.u[1] = w1; x.u[2] = w2; x.u[3] = w3;
    return x.v;
}

static __device__ __forceinline__ f32x16 mf(bf16x8 a, bf16x8 b, f32x16 c) {
    return __builtin_amdgcn_mfma_f32_32x32x16_bf16(a, b, c, 0, 0, 0);
}

// Cross-half exchange. a_out = [a@lo-half, b@lo-half] (hi lanes receive b from
// lane-32); b_out = [a@hi-half, b@hi-half] (lo lanes receive a from lane+32).
#if __has_builtin(__builtin_amdgcn_permlane32_swap)
static __device__ __forceinline__ void xswap(unsigned a, unsigned b,
                                             unsigned& a_out, unsigned& b_out) {
    i32x2 r = __builtin_amdgcn_permlane32_swap((int)a, (int)b, false, false);
    a_out = (unsigned)r[0];
    b_out = (unsigned)r[1];
}
#else
static __device__ __forceinline__ void xswap(unsigned a, unsigned b,
                                             unsigned& a_out, unsigned& b_out) {
    const int lane = threadIdx.x & 63;
    const int idx = (lane ^ 32) << 2;
    unsigned sa = (unsigned)__builtin_amdgcn_ds_bpermute(idx, (int)a);
    unsigned sb = (unsigned)__builtin_amdgcn_ds_bpermute(idx, (int)b);
    const bool hi = lane >= 32;
    a_out = hi ? sb : a;
    b_out = hi ? b : sa;
}
#endif

// Build the two K-tile B-fragments (hi & lo) for a 32-dim vector h held in
// D-layout (16 regs: rows (r&3)+8*(r>>2)+4*half, col = lane&31).
static __device__ __forceinline__ void hfrag(const f32x16& h, bool hi,
                                             bf16x8& B0h, bf16x8& B0l,
                                             bf16x8& B1h, bf16x8& B1l) {
    unsigned Wh[8], Wl[8];
#pragma unroll
    for (int p = 0; p < 8; ++p) split2(h[2 * p], h[2 * p + 1], Wh[p], Wl[p]);
    unsigned a02h, b02h, a02l, b02l, a13h, b13h, a13l, b13l;
    xswap(Wh[0], Wh[2], a02h, b02h); xswap(Wl[0], Wl[2], a02l, b02l);
    xswap(Wh[1], Wh[3], a13h, b13h); xswap(Wl[1], Wl[3], a13l, b13l);
    B0h = mkfrag(hi ? a02h : Wh[0], hi ? a13h : Wh[1],
                 hi ? Wh[2] : b02h, hi ? Wh[3] : b13h);
    B0l = mkfrag(hi ? a02l : Wl[0], hi ? a13l : Wl[1],
                 hi ? Wl[2] : b02l, hi ? Wl[3] : b13l);
    unsigned a46h, b46h, a46l, b46l, a57h, b57h, a57l, b57l;
    xswap(Wh[4], Wh[6], a46h, b46h); xswap(Wl[4], Wl[6], a46l, b46l);
    xswap(Wh[5], Wh[7], a57h, b57h); xswap(Wl[5], Wl[7], a57l, b57l);
    B1h = mkfrag(hi ? a46h : Wh[4], hi ? a57h : Wh[5],
                 hi ? Wh[6] : b46h, hi ? Wh[7] : b57h);
    B1l = mkfrag(hi ? a46l : Wl[4], hi ? a57l : Wl[5],
                 hi ? Wl[6] : b46l, hi ? Wl[7] : b57l);
}

__global__ __launch_bounds__(256, 2)
void emulator_kernel(const float* __restrict__ phys,
                     const float* __restrict__ latents,
                     const float* __restrict__ W1g,
                     const float* __restrict__ b1g,
                     const float* __restrict__ W2g,
                     const float* __restrict__ b2g,
                     const float* __restrict__ W3g,
                     const float* __restrict__ b3g,
                     float* __restrict__ out) {
    const int tid = threadIdx.x;
    const int lane = tid & 63;
    const int wv = tid >> 6;
    const int c = lane & 31;             // batch col AND weight out-dim (A m)
    const bool hi = lane >= 32;          // k-half
    const int kb = hi ? 8 : 0;
    const int r = blockIdx.x * 128 + wv * 32 + c;   // batch row

    // ---- pinned A-frags (W^T tiles, bf16 hi/lo) ----
    bf16x8 A1t0h, A1t0l, A1t1h, A1t1l;
    {
        unsigned hw[4], lw[4];
#pragma unroll
        for (int w = 0; w < 4; ++w) {
            const int k0 = kb + 2 * w;
            split2(W1g[k0 * HH + c], W1g[(k0 + 1) * HH + c], hw[w], lw[w]);
        }
        A1t0h = mkfrag(hw[0], hw[1], hw[2], hw[3]);
        A1t0l = mkfrag(lw[0], lw[1], lw[2], lw[3]);
        const float e0 = hi ? 0.0f : W1g[16 * HH + c];
        const float e1 = hi ? 0.0f : W1g[17 * HH + c];
        unsigned h0, l0;
        split2(e0, e1, h0, l0);
        A1t1h = mkfrag(h0, 0, 0, 0);
        A1t1l = mkfrag(l0, 0, 0, 0);
    }
    bf16x8 A2h[2], A2l[2], A3h[2], A3l[2];
#pragma unroll
    for (int t2 = 0; t2 < 2; ++t2) {
        unsigned hw[4], lw[4];
#pragma unroll
        for (int w = 0; w < 4; ++w) {
            const int k0 = 16 * t2 + kb + 2 * w;
            split2(W2g[k0 * HH + c], W2g[(k0 + 1) * HH + c], hw[w], lw[w]);
        }
        A2h[t2] = mkfrag(hw[0], hw[1], hw[2], hw[3]);
        A2l[t2] = mkfrag(lw[0], lw[1], lw[2], lw[3]);
    }
#pragma unroll
    for (int t2 = 0; t2 < 2; ++t2) {
        unsigned hw[4], lw[4];
#pragma unroll
        for (int w = 0; w < 4; ++w) {
            const int k0 = 16 * t2 + kb + 2 * w;
            const float e0 = (c < LL) ? W3g[k0 * LL + c] : 0.0f;
            const float e1 = (c < LL) ? W3g[(k0 + 1) * LL + c] : 0.0f;
            split2(e0, e1, hw[w], lw[w]);
        }
        A3h[t2] = mkfrag(hw[0], hw[1], hw[2], hw[3]);
        A3l[t2] = mkfrag(lw[0], lw[1], lw[2], lw[3]);
    }

    // ---- bias C-frags (D-layout) ----
    f32x16 cb1, cb2, cb3;
#pragma unroll
    for (int rr = 0; rr < 16; ++rr) {
        const int row = (rr & 3) + 8 * (rr >> 2) + (hi ? 4 : 0);
        cb1[rr] = b1g[row];
        cb2[rr] = b2g[row];
        cb3[rr] = (row < LL) ? b3g[row] : 0.0f;
    }

    // ---- latent state in D-layout (meaningful regs only; rest 0) ----
    f32x16 lat;
#pragma unroll
    for (int i = 0; i < 16; ++i) lat[i] = 0.0f;
    {
        const float* lrow = latents + (size_t)r * LL;
        const float2* p01 = reinterpret_cast<const float2*>(lrow + (hi ? 4 : 0));
        const float2 v0 = p01[0], v1 = p01[1];
        lat[0] = v0.x; lat[1] = v0.y; lat[2] = v1.x; lat[3] = v1.y;
        const float2 v2 = reinterpret_cast<const float2*>(lrow + (hi ? 12 : 8))[0];
        lat[4] = v2.x; lat[5] = v2.y;
        if (!hi) {
            const float2 v3 = reinterpret_cast<const float2*>(lrow + 10)[0];
            lat[6] = v3.x; lat[7] = v3.y;
        }
    }

    const float4* pv = reinterpret_cast<const float4*>(phys) + (size_t)r * TT;
    float4 ph = pv[0];
    float* outr = out + (size_t)r * TT * LL;

#pragma unroll 1
    for (int t = 0; t < TT; ++t) {
        const float4 phn = pv[(t < TT - 1) ? (t + 1) : t];

        // ---- L1 B-frags from x = [ph(4), lat(14)] ----
        unsigned X0h, X0l, X1h, X1l, X2h, X2l, X3h, X3l, P0h, P0l, P1h, P1l;
        split2(lat[0], lat[1], X0h, X0l);
        split2(lat[2], lat[3], X1h, X1l);
        split2(lat[4], lat[5], X2h, X2l);
        split2(lat[6], lat[7], X3h, X3l);
        split2(ph.x, ph.y, P0h, P0l);
        split2(ph.z, ph.w, P1h, P1l);
        unsigned a2h, b2h, a2l, b2l, a3h, b3h, a3l, b3l;
        xswap(X2h, X2h, a2h, b2h); xswap(X2l, X2l, a2l, b2l);
        xswap(X3h, X3h, a3h, b3h); xswap(X3l, X3l, a3l, b3l);
        bf16x8 B0h = mkfrag(hi ? X0h : P0h, hi ? X1h : P1h,
                            hi ? a2h : X0h, hi ? a3h : X1h);
        bf16x8 B0l = mkfrag(hi ? X0l : P0l, hi ? X1l : P1l,
                            hi ? a2l : X0l, hi ? a3l : X1l);
        bf16x8 B1h = mkfrag(b2h, 0, 0, 0);   // half0: (lat12,13); half1: x A=0
        bf16x8 B1l = mkfrag(b2l, 0, 0, 0);

        // ---- L1 ----
        f32x16 acc = mf(A1t0l, B0h, mf(A1t0h, B0l, mf(A1t0h, B0h, cb1)));
        acc = mf(A1t1l, B1h, mf(A1t1h, B1l, mf(A1t1h, B1h, acc)));
        f32x16 h1v;
#pragma unroll
        for (int i = 0; i < 16; ++i) h1v[i] = fmaxf(acc[i], 0.0f);

        // ---- L2 ----
        bf16x8 C0h, C0l, C1h, C1l;
        hfrag(h1v, hi, C0h, C0l, C1h, C1l);
        f32x16 acc2 = mf(A2l[0], C0h, mf(A2h[0], C0l, mf(A2h[0], C0h, cb2)));
        acc2 = mf(A2l[1], C1h, mf(A2h[1], C1l, mf(A2h[1], C1h, acc2)));
        f32x16 h2v;
#pragma unroll
        for (int i = 0; i < 16; ++i) h2v[i] = fmaxf(acc2[i], 0.0f);

        // ---- L3 + residual (C = lat + b3) ----
        bf16x8 D0h, D0l, D1h, D1l;
        hfrag(h2v, hi, D0h, D0l, D1h, D1l);
        f32x16 c3;
#pragma unroll
        for (int i = 0; i < 16; ++i) c3[i] = lat[i] + cb3[i];
        f32x16 nl = mf(A3l[0], D0h, mf(A3h[0], D0l, mf(A3h[0], D0h, c3)));
        nl = mf(A3l[1], D1h, mf(A3h[1], D1l, mf(A3h[1], D1h, nl)));
        lat = nl;

        // ---- store out[r][t][:] (rows: h0 -> 0-3,8-11; h1 -> 4-7,12-13) ----
        float* ob = outr + (size_t)t * LL;
        const int o0 = hi ? 4 : 0;
        *reinterpret_cast<float2*>(ob + o0)     = make_float2(lat[0], lat[1]);
        *reinterpret_cast<float2*>(ob + o0 + 2) = make_float2(lat[2], lat[3]);
        *reinterpret_cast<float2*>(ob + (hi ? 12 : 8)) = make_float2(lat[4], lat[5]);
        if (!hi)
            *reinterpret_cast<float2*>(ob + 10) = make_float2(lat[6], lat[7]);

        ph = phn;
    }
}

extern "C" void kernel_launch(void* const* d_in, const int* in_sizes, int n_in,
                              void* d_out, int out_size, void* d_ws, size_t ws_size,
                              hipStream_t stream) {
    const float* phys    = (const float*)d_in[0];
    const float* latents = (const float*)d_in[1];
    const float* W1      = (const float*)d_in[2];
    const float* b1      = (const float*)d_in[3];
    const float* W2      = (const float*)d_in[4];
    const float* b2      = (const float*)d_in[5];
    const float* W3      = (const float*)d_in[6];
    const float* b3      = (const float*)d_in[7];
    float* out = (float*)d_out;

    const int threads = 256;             // 4 waves x 32 rows = 128 rows/block
    const int blocks = BB / 128;         // 512 blocks -> 2 waves/SIMD
    emulator_kernel<<<blocks, threads, 0, stream>>>(
        phys, latents, W1, b1, W2, b2, W3, b3, out);
}

// Round 12
// 629.221 us; speedup vs baseline: 6.3563x; 1.0597x over previous
//
#include <hip/hip_runtime.h>

// Recurrent MLP emulator: B=65536 rows, T=256 steps, MLP 18->32->32->14.
// 32x32x16 MFMA, split-bf16 fp32 emulation, permlane32_swap regrouping.
// R12 changes vs R11 (dur flat at 667us, VGPR=80 -> remat diagnosis):
//  1. FORCE-PIN all loop-invariant weight/bias fragments in VGPRs with an
//     empty per-iteration asm "+v" — compiler can no longer rematerialize
//     them as per-step L2 reloads (the hidden ~700 VALU instrs/wave-step).
//  2. hfrag: the 16 cndmasks were redundant — permlane32_swap's two outputs
//     ARE the per-half selects. Use them directly.
//  3. L1 tail tile (x dims 16,17): 3 MFMAs -> 1 by packing hi*hi, hi*lo,
//     lo*hi into 6 k-slots of one tile (hi-half A zeroed, no double count).

#define BB 65536
#define TT 256
#define LL 14
#define HH 32

typedef float f32x16 __attribute__((ext_vector_type(16)));
typedef __bf16 bf16x8 __attribute__((ext_vector_type(8)));
typedef int i32x2 __attribute__((ext_vector_type(2)));

static __device__ __forceinline__ void split2(float v0, float v1,
                                              unsigned& hw, unsigned& lw) {
    unsigned u0 = __float_as_uint(v0), u1 = __float_as_uint(v1);
    unsigned h0 = (u0 + 0x8000u) & 0xFFFF0000u;
    unsigned h1 = (u1 + 0x8000u) & 0xFFFF0000u;
    float l0 = v0 - __uint_as_float(h0);
    float l1 = v1 - __uint_as_float(h1);
    unsigned s0 = __float_as_uint(l0), s1 = __float_as_uint(l1);
    hw = (h0 >> 16) | h1;
    lw = ((s0 + 0x8000u) >> 16) | ((s1 + 0x8000u) & 0xFFFF0000u);
}

static __device__ __forceinline__ bf16x8 mkfrag(unsigned w0, unsigned w1,
                                                unsigned w2, unsigned w3) {
    union { unsigned u[4]; bf16x8 v; } x;
    x.u[0] = w0; x.u[1] = w1; x.u[2] = w2; x.u[3] = w3;
    return x.v;
}

static __device__ __forceinline__ f32x16 mf(bf16x8 a, bf16x8 b, f32x16 c) {
    return __builtin_amdgcn_mfma_f32_32x32x16_bf16(a, b, c, 0, 0, 0);
}

// Cross-half exchange: a_out = [a@lo-half | b@lo-half(from lane-32)],
// b_out = [a@hi-half(from lane+32) | b@hi-half].
#if __has_builtin(__builtin_amdgcn_permlane32_swap)
static __device__ __forceinline__ void xswap(unsigned a, unsigned b,
                                             unsigned& a_out, unsigned& b_out) {
    i32x2 r = __builtin_amdgcn_permlane32_swap((int)a, (int)b, false, false);
    a_out = (unsigned)r[0];
    b_out = (unsigned)r[1];
}
#else
static __device__ __forceinline__ void xswap(unsigned a, unsigned b,
                                             unsigned& a_out, unsigned& b_out) {
    const int lane = threadIdx.x & 63;
    const int idx = (lane ^ 32) << 2;
    unsigned sa = (unsigned)__builtin_amdgcn_ds_bpermute(idx, (int)a);
    unsigned sb = (unsigned)__builtin_amdgcn_ds_bpermute(idx, (int)b);
    const bool hi = lane >= 32;
    a_out = hi ? sb : a;
    b_out = hi ? b : sa;
}
#endif

// D-layout 32-vector -> two K-tile B-frag pairs. No selects needed:
// xswap outputs are exactly the per-half words.
static __device__ __forceinline__ void hfrag(const f32x16& h,
                                             bf16x8& B0h, bf16x8& B0l,
                                             bf16x8& B1h, bf16x8& B1l) {
    unsigned Wh[8], Wl[8];
#pragma unroll
    for (int p = 0; p < 8; ++p) split2(h[2 * p], h[2 * p + 1], Wh[p], Wl[p]);
    unsigned a02h, b02h, a02l, b02l, a13h, b13h, a13l, b13l;
    xswap(Wh[0], Wh[2], a02h, b02h); xswap(Wl[0], Wl[2], a02l, b02l);
    xswap(Wh[1], Wh[3], a13h, b13h); xswap(Wl[1], Wl[3], a13l, b13l);
    B0h = mkfrag(a02h, a13h, b02h, b13h);
    B0l = mkfrag(a02l, a13l, b02l, b13l);
    unsigned a46h, b46h, a46l, b46l, a57h, b57h, a57l, b57l;
    xswap(Wh[4], Wh[6], a46h, b46h); xswap(Wl[4], Wl[6], a46l, b46l);
    xswap(Wh[5], Wh[7], a57h, b57h); xswap(Wl[5], Wl[7], a57l, b57l);
    B1h = mkfrag(a46h, a57h, b46h, b57h);
    B1l = mkfrag(a46l, a57l, b46l, b57l);
}

__global__ __launch_bounds__(256, 2)
void emulator_kernel(const float* __restrict__ phys,
                     const float* __restrict__ latents,
                     const float* __restrict__ W1g,
                     const float* __restrict__ b1g,
                     const float* __restrict__ W2g,
                     const float* __restrict__ b2g,
                     const float* __restrict__ W3g,
                     const float* __restrict__ b3g,
                     float* __restrict__ out) {
    const int tid = threadIdx.x;
    const int lane = tid & 63;
    const int wv = tid >> 6;
    const int c = lane & 31;             // batch col AND weight out-dim (A m)
    const bool hi = lane >= 32;          // k-half
    const int kb = hi ? 8 : 0;
    const int r = blockIdx.x * 128 + wv * 32 + c;   // batch row

    // ---- pinned A-frags (W^T tiles, bf16 hi/lo) ----
    bf16x8 A1t0h, A1t0l, A1c;
    {
        unsigned hw[4], lw[4];
#pragma unroll
        for (int w = 0; w < 4; ++w) {
            const int k0 = kb + 2 * w;
            split2(W1g[k0 * HH + c], W1g[(k0 + 1) * HH + c], hw[w], lw[w]);
        }
        A1t0h = mkfrag(hw[0], hw[1], hw[2], hw[3]);
        A1t0l = mkfrag(lw[0], lw[1], lw[2], lw[3]);
        // Tail tile (x dims 16,17), consolidated: A = [Whp, Whp, Wlp, 0] on
        // the lo k-half; zero on the hi k-half (avoids double counting).
        unsigned whp, wlp;
        split2(W1g[16 * HH + c], W1g[17 * HH + c], whp, wlp);
        A1c = hi ? mkfrag(0, 0, 0, 0) : mkfrag(whp, whp, wlp, 0);
    }
    bf16x8 A2h0, A2l0, A2h1, A2l1, A3h0, A3l0, A3h1, A3l1;
    {
        unsigned hw[4], lw[4];
#pragma unroll
        for (int w = 0; w < 4; ++w) {
            const int k0 = kb + 2 * w;
            split2(W2g[k0 * HH + c], W2g[(k0 + 1) * HH + c], hw[w], lw[w]);
        }
        A2h0 = mkfrag(hw[0], hw[1], hw[2], hw[3]);
        A2l0 = mkfrag(lw[0], lw[1], lw[2], lw[3]);
#pragma unroll
        for (int w = 0; w < 4; ++w) {
            const int k0 = 16 + kb + 2 * w;
            split2(W2g[k0 * HH + c], W2g[(k0 + 1) * HH + c], hw[w], lw[w]);
        }
        A2h1 = mkfrag(hw[0], hw[1], hw[2], hw[3]);
        A2l1 = mkfrag(lw[0], lw[1], lw[2], lw[3]);
#pragma unroll
        for (int w = 0; w < 4; ++w) {
            const int k0 = kb + 2 * w;
            const float e0 = (c < LL) ? W3g[k0 * LL + c] : 0.0f;
            const float e1 = (c < LL) ? W3g[(k0 + 1) * LL + c] : 0.0f;
            split2(e0, e1, hw[w], lw[w]);
        }
        A3h0 = mkfrag(hw[0], hw[1], hw[2], hw[3]);
        A3l0 = mkfrag(lw[0], lw[1], lw[2], lw[3]);
#pragma unroll
        for (int w = 0; w < 4; ++w) {
            const int k0 = 16 + kb + 2 * w;
            const float e0 = (c < LL) ? W3g[k0 * LL + c] : 0.0f;
            const float e1 = (c < LL) ? W3g[(k0 + 1) * LL + c] : 0.0f;
            split2(e0, e1, hw[w], lw[w]);
        }
        A3h1 = mkfrag(hw[0], hw[1], hw[2], hw[3]);
        A3l1 = mkfrag(lw[0], lw[1], lw[2], lw[3]);
    }

    // ---- bias C-frags (D-layout) ----
    f32x16 cb1, cb2, cb3;
#pragma unroll
    for (int rr = 0; rr < 16; ++rr) {
        const int row = (rr & 3) + 8 * (rr >> 2) + (hi ? 4 : 0);
        cb1[rr] = b1g[row];
        cb2[rr] = b2g[row];
        cb3[rr] = (row < LL) ? b3g[row] : 0.0f;
    }

    // ---- latent state in D-layout (regs 0-7 meaningful; 8-15 stay 0) ----
    f32x16 lat;
#pragma unroll
    for (int i = 0; i < 16; ++i) lat[i] = 0.0f;
    {
        const float* lrow = latents + (size_t)r * LL;
        const float2* p01 = reinterpret_cast<const float2*>(lrow + (hi ? 4 : 0));
        const float2 v0 = p01[0], v1 = p01[1];
        lat[0] = v0.x; lat[1] = v0.y; lat[2] = v1.x; lat[3] = v1.y;
        const float2 v2 = reinterpret_cast<const float2*>(lrow + (hi ? 12 : 8))[0];
        lat[4] = v2.x; lat[5] = v2.y;
        if (!hi) {
            const float2 v3 = reinterpret_cast<const float2*>(lrow + 10)[0];
            lat[6] = v3.x; lat[7] = v3.y;
        }
    }

    const float4* pv = reinterpret_cast<const float4*>(phys) + (size_t)r * TT;
    float4 ph = pv[0];
    float* outr = out + (size_t)r * TT * LL;

#pragma unroll 1
    for (int t = 0; t < TT; ++t) {
        // FORCE-PIN: mark every loop-invariant fragment as asm-modified so
        // the compiler cannot rematerialize them from memory per step.
        asm volatile("" : "+v"(A1t0h), "+v"(A1t0l), "+v"(A1c),
                          "+v"(A2h0), "+v"(A2l0), "+v"(A2h1), "+v"(A2l1),
                          "+v"(A3h0), "+v"(A3l0), "+v"(A3h1), "+v"(A3l1));
        asm volatile("" : "+v"(cb1), "+v"(cb2), "+v"(cb3));

        const float4 phn = pv[(t < TT - 1) ? (t + 1) : t];

        // ---- L1 B-frags from x = [ph(4), lat(14)] ----
        unsigned X0h, X0l, X1h, X1l, X2h, X2l, X3h, X3l, P0h, P0l, P1h, P1l;
        split2(lat[0], lat[1], X0h, X0l);
        split2(lat[2], lat[3], X1h, X1l);
        split2(lat[4], lat[5], X2h, X2l);
        split2(lat[6], lat[7], X3h, X3l);
        split2(ph.x, ph.y, P0h, P0l);
        split2(ph.z, ph.w, P1h, P1l);
        unsigned a2h, b2h, a2l, b2l, a3h, b3h, a3l, b3l;
        xswap(X2h, X2h, a2h, b2h); xswap(X2l, X2l, a2l, b2l);
        xswap(X3h, X3h, a3h, b3h); xswap(X3l, X3l, a3l, b3l);
        bf16x8 B0h = mkfrag(hi ? X0h : P0h, hi ? X1h : P1h,
                            hi ? a2h : X0h, hi ? a3h : X1h);
        bf16x8 B0l = mkfrag(hi ? X0l : P0l, hi ? X1l : P1l,
                            hi ? a2l : X0l, hi ? a3l : X1l);
        // Consolidated tail tile B: [xh(16,17), xl(16,17), xh(16,17), 0]
        bf16x8 B1c = mkfrag(b2h, b2l, b2h, 0);

        // ---- L1: 4 MFMAs ----
        f32x16 acc = mf(A1t0l, B0h, mf(A1t0h, B0l, mf(A1t0h, B0h, cb1)));
        acc = mf(A1c, B1c, acc);
        f32x16 h1v;
#pragma unroll
        for (int i = 0; i < 16; ++i) h1v[i] = fmaxf(acc[i], 0.0f);

        // ---- L2: 6 MFMAs ----
        bf16x8 C0h, C0l, C1h, C1l;
        hfrag(h1v, C0h, C0l, C1h, C1l);
        f32x16 acc2 = mf(A2l0, C0h, mf(A2h0, C0l, mf(A2h0, C0h, cb2)));
        acc2 = mf(A2l1, C1h, mf(A2h1, C1l, mf(A2h1, C1h, acc2)));
        f32x16 h2v;
#pragma unroll
        for (int i = 0; i < 16; ++i) h2v[i] = fmaxf(acc2[i], 0.0f);

        // ---- L3 + residual (C = lat + b3): 6 MFMAs ----
        bf16x8 D0h, D0l, D1h, D1l;
        hfrag(h2v, D0h, D0l, D1h, D1l);
        f32x16 c3;
#pragma unroll
        for (int i = 0; i < 16; ++i) c3[i] = lat[i] + cb3[i];
        f32x16 nl = mf(A3l0, D0h, mf(A3h0, D0l, mf(A3h0, D0h, c3)));
        nl = mf(A3l1, D1h, mf(A3h1, D1l, mf(A3h1, D1h, nl)));
        lat = nl;

        // ---- store out[r][t][:] ----
        float* ob = outr + (size_t)t * LL;
        const int o0 = hi ? 4 : 0;
        *reinterpret_cast<float2*>(ob + o0)     = make_float2(lat[0], lat[1]);
        *reinterpret_cast<float2*>(ob + o0 + 2) = make_float2(lat[2], lat[3]);
        *reinterpret_cast<float2*>(ob + (hi ? 12 : 8)) = make_float2(lat[4], lat[5]);
        if (!hi)
            *reinterpret_cast<float2*>(ob + 10) = make_float2(lat[6], lat[7]);

        ph = phn;
    }
}

extern "C" void kernel_launch(void* const* d_in, const int* in_sizes, int n_in,
                              void* d_out, int out_size, void* d_ws, size_t ws_size,
                              hipStream_t stream) {
    const float* phys    = (const float*)d_in[0];
    const float* latents = (const float*)d_in[1];
    const float* W1      = (const float*)d_in[2];
    const float* b1      = (const float*)d_in[3];
    const float* W2      = (const float*)d_in[4];
    const float* b2      = (const float*)d_in[5];
    const float* W3      = (const float*)d_in[6];
    const float* b3      = (const float*)d_in[7];
    float* out = (float*)d_out;

    const int threads = 256;             // 4 waves x 32 rows = 128 rows/block
    const int blocks = BB / 128;         // 512 blocks -> 2 waves/SIMD
    emulator_kernel<<<blocks, threads, 0, stream>>>(
        phys, latents, W1, b1, W2, b2, W3, b3, out);
}

// Round 13
// 600.421 us; speedup vs baseline: 6.6612x; 1.0480x over previous
//
#include <hip/hip_runtime.h>

// Recurrent MLP emulator: B=65536 rows, T=256 steps, MLP 18->32->32->14.
// 32x32x16 MFMA, split-bf16 fp32 emulation, permlane32_swap regrouping.
// R13 changes vs R12 (629us; VALU ~780 instr/wave-step, ~2.5K cyc/step stall):
//  1. split2 via (__bf16) casts + bf16x2 build -> v_cvt_pk_bf16_f32 (RTNE),
//     ~7 VALU instead of ~13 bit-trick ops. 22 splits/step -> -130 VALU.
//  2. Each layer's 6 (or 4) serial MFMAs split into TWO independent 3-chains
//     (second chain starts from a pinned loop-invariant zero C-frag), summed
//     at the ReLU. MFMA critical path 16-deep -> 9-deep per step.
//  3. s_setprio(1) around MFMA clusters (2 barrier-free waves/SIMD drift ->
//     the regime where setprio pays).

#define BB 65536
#define TT 256
#define LL 14
#define HH 32

typedef float f32x16 __attribute__((ext_vector_type(16)));
typedef __bf16 bf16x8 __attribute__((ext_vector_type(8)));
typedef __bf16 bf16x2 __attribute__((ext_vector_type(2)));
typedef int i32x2 __attribute__((ext_vector_type(2)));

// Pack two floats to bf16 pair (RTNE) -> unsigned word. Compiler emits
// v_cvt_pk_bf16_f32 for this build_vector pattern.
static __device__ __forceinline__ unsigned packbf(float a, float b) {
    bf16x2 p;
    p[0] = (__bf16)a;
    p[1] = (__bf16)b;
    return __builtin_bit_cast(unsigned, p);
}

static __device__ __forceinline__ void split2(float v0, float v1,
                                              unsigned& hw, unsigned& lw) {
    const __bf16 h0 = (__bf16)v0, h1 = (__bf16)v1;
    hw = packbf(v0, v1);                 // CSEs with h0/h1 converts
    const float l0 = v0 - (float)h0;
    const float l1 = v1 - (float)h1;
    lw = packbf(l0, l1);
}

static __device__ __forceinline__ bf16x8 mkfrag(unsigned w0, unsigned w1,
                                                unsigned w2, unsigned w3) {
    union { unsigned u[4]; bf16x8 v; } x;
    x.u[0] = w0; x.u[1] = w1; x.u[2] = w2; x.u[3] = w3;
    return x.v;
}

static __device__ __forceinline__ f32x16 mf(bf16x8 a, bf16x8 b, f32x16 c) {
    return __builtin_amdgcn_mfma_f32_32x32x16_bf16(a, b, c, 0, 0, 0);
}

// Cross-half exchange: a_out = [a@lo | b@(lane-32)], b_out = [a@(lane+32) | b@hi].
#if __has_builtin(__builtin_amdgcn_permlane32_swap)
static __device__ __forceinline__ void xswap(unsigned a, unsigned b,
                                             unsigned& a_out, unsigned& b_out) {
    i32x2 r = __builtin_amdgcn_permlane32_swap((int)a, (int)b, false, false);
    a_out = (unsigned)r[0];
    b_out = (unsigned)r[1];
}
#else
static __device__ __forceinline__ void xswap(unsigned a, unsigned b,
                                             unsigned& a_out, unsigned& b_out) {
    const int lane = threadIdx.x & 63;
    const int idx = (lane ^ 32) << 2;
    unsigned sa = (unsigned)__builtin_amdgcn_ds_bpermute(idx, (int)a);
    unsigned sb = (unsigned)__builtin_amdgcn_ds_bpermute(idx, (int)b);
    const bool hi = lane >= 32;
    a_out = hi ? sb : a;
    b_out = hi ? b : sa;
}
#endif

// D-layout 32-vector -> two K-tile B-frag pairs (no selects: xswap outputs
// are exactly the per-half words).
static __device__ __forceinline__ void hfrag(const f32x16& h,
                                             bf16x8& B0h, bf16x8& B0l,
                                             bf16x8& B1h, bf16x8& B1l) {
    unsigned Wh[8], Wl[8];
#pragma unroll
    for (int p = 0; p < 8; ++p) split2(h[2 * p], h[2 * p + 1], Wh[p], Wl[p]);
    unsigned a02h, b02h, a02l, b02l, a13h, b13h, a13l, b13l;
    xswap(Wh[0], Wh[2], a02h, b02h); xswap(Wl[0], Wl[2], a02l, b02l);
    xswap(Wh[1], Wh[3], a13h, b13h); xswap(Wl[1], Wl[3], a13l, b13l);
    B0h = mkfrag(a02h, a13h, b02h, b13h);
    B0l = mkfrag(a02l, a13l, b02l, b13l);
    unsigned a46h, b46h, a46l, b46l, a57h, b57h, a57l, b57l;
    xswap(Wh[4], Wh[6], a46h, b46h); xswap(Wl[4], Wl[6], a46l, b46l);
    xswap(Wh[5], Wh[7], a57h, b57h); xswap(Wl[5], Wl[7], a57l, b57l);
    B1h = mkfrag(a46h, a57h, b46h, b57h);
    B1l = mkfrag(a46l, a57l, b46l, b57l);
}

__global__ __launch_bounds__(256, 2)
void emulator_kernel(const float* __restrict__ phys,
                     const float* __restrict__ latents,
                     const float* __restrict__ W1g,
                     const float* __restrict__ b1g,
                     const float* __restrict__ W2g,
                     const float* __restrict__ b2g,
                     const float* __restrict__ W3g,
                     const float* __restrict__ b3g,
                     float* __restrict__ out) {
    const int tid = threadIdx.x;
    const int lane = tid & 63;
    const int wv = tid >> 6;
    const int c = lane & 31;
    const bool hi = lane >= 32;
    const int kb = hi ? 8 : 0;
    const int r = blockIdx.x * 128 + wv * 32 + c;

    // ---- pinned A-frags (W^T tiles, bf16 hi/lo) ----
    bf16x8 A1t0h, A1t0l, A1c;
    {
        unsigned hw[4], lw[4];
#pragma unroll
        for (int w = 0; w < 4; ++w) {
            const int k0 = kb + 2 * w;
            split2(W1g[k0 * HH + c], W1g[(k0 + 1) * HH + c], hw[w], lw[w]);
        }
        A1t0h = mkfrag(hw[0], hw[1], hw[2], hw[3]);
        A1t0l = mkfrag(lw[0], lw[1], lw[2], lw[3]);
        unsigned whp, wlp;
        split2(W1g[16 * HH + c], W1g[17 * HH + c], whp, wlp);
        A1c = hi ? mkfrag(0, 0, 0, 0) : mkfrag(whp, whp, wlp, 0);
    }
    bf16x8 A2h0, A2l0, A2h1, A2l1, A3h0, A3l0, A3h1, A3l1;
    {
        unsigned hw[4], lw[4];
#pragma unroll
        for (int w = 0; w < 4; ++w) {
            const int k0 = kb + 2 * w;
            split2(W2g[k0 * HH + c], W2g[(k0 + 1) * HH + c], hw[w], lw[w]);
        }
        A2h0 = mkfrag(hw[0], hw[1], hw[2], hw[3]);
        A2l0 = mkfrag(lw[0], lw[1], lw[2], lw[3]);
#pragma unroll
        for (int w = 0; w < 4; ++w) {
            const int k0 = 16 + kb + 2 * w;
            split2(W2g[k0 * HH + c], W2g[(k0 + 1) * HH + c], hw[w], lw[w]);
        }
        A2h1 = mkfrag(hw[0], hw[1], hw[2], hw[3]);
        A2l1 = mkfrag(lw[0], lw[1], lw[2], lw[3]);
#pragma unroll
        for (int w = 0; w < 4; ++w) {
            const int k0 = kb + 2 * w;
            const float e0 = (c < LL) ? W3g[k0 * LL + c] : 0.0f;
            const float e1 = (c < LL) ? W3g[(k0 + 1) * LL + c] : 0.0f;
            split2(e0, e1, hw[w], lw[w]);
        }
        A3h0 = mkfrag(hw[0], hw[1], hw[2], hw[3]);
        A3l0 = mkfrag(lw[0], lw[1], lw[2], lw[3]);
#pragma unroll
        for (int w = 0; w < 4; ++w) {
            const int k0 = 16 + kb + 2 * w;
            const float e0 = (c < LL) ? W3g[k0 * LL + c] : 0.0f;
            const float e1 = (c < LL) ? W3g[(k0 + 1) * LL + c] : 0.0f;
            split2(e0, e1, hw[w], lw[w]);
        }
        A3h1 = mkfrag(hw[0], hw[1], hw[2], hw[3]);
        A3l1 = mkfrag(lw[0], lw[1], lw[2], lw[3]);
    }

    // ---- bias C-frags (D-layout) + pinned zero C-frag ----
    f32x16 cb1, cb2, cb3, z;
#pragma unroll
    for (int rr = 0; rr < 16; ++rr) {
        const int row = (rr & 3) + 8 * (rr >> 2) + (hi ? 4 : 0);
        cb1[rr] = b1g[row];
        cb2[rr] = b2g[row];
        cb3[rr] = (row < LL) ? b3g[row] : 0.0f;
        z[rr] = 0.0f;
    }

    // ---- latent state in D-layout (regs 0-7 meaningful; 8-15 stay 0) ----
    f32x16 lat;
#pragma unroll
    for (int i = 0; i < 16; ++i) lat[i] = 0.0f;
    {
        const float* lrow = latents + (size_t)r * LL;
        const float2* p01 = reinterpret_cast<const float2*>(lrow + (hi ? 4 : 0));
        const float2 v0 = p01[0], v1 = p01[1];
        lat[0] = v0.x; lat[1] = v0.y; lat[2] = v1.x; lat[3] = v1.y;
        const float2 v2 = reinterpret_cast<const float2*>(lrow + (hi ? 12 : 8))[0];
        lat[4] = v2.x; lat[5] = v2.y;
        if (!hi) {
            const float2 v3 = reinterpret_cast<const float2*>(lrow + 10)[0];
            lat[6] = v3.x; lat[7] = v3.y;
        }
    }

    const float4* pv = reinterpret_cast<const float4*>(phys) + (size_t)r * TT;
    float4 ph = pv[0];
    float* outr = out + (size_t)r * TT * LL;

#pragma unroll 1
    for (int t = 0; t < TT; ++t) {
        // FORCE-PIN all loop-invariant fragments (incl. the zero C-frag).
        asm volatile("" : "+v"(A1t0h), "+v"(A1t0l), "+v"(A1c),
                          "+v"(A2h0), "+v"(A2l0), "+v"(A2h1), "+v"(A2l1),
                          "+v"(A3h0), "+v"(A3l0), "+v"(A3h1), "+v"(A3l1),
                          "+v"(cb1), "+v"(cb2), "+v"(cb3), "+v"(z));

        const float4 phn = pv[(t < TT - 1) ? (t + 1) : t];

        // ---- L1 B-frags from x = [ph(4), lat(14)] ----
        unsigned X0h, X0l, X1h, X1l, X2h, X2l, X3h, X3l, P0h, P0l, P1h, P1l;
        split2(lat[0], lat[1], X0h, X0l);
        split2(lat[2], lat[3], X1h, X1l);
        split2(lat[4], lat[5], X2h, X2l);
        split2(lat[6], lat[7], X3h, X3l);
        split2(ph.x, ph.y, P0h, P0l);
        split2(ph.z, ph.w, P1h, P1l);
        unsigned a2h, b2h, a2l, b2l, a3h, b3h, a3l, b3l;
        xswap(X2h, X2h, a2h, b2h); xswap(X2l, X2l, a2l, b2l);
        xswap(X3h, X3h, a3h, b3h); xswap(X3l, X3l, a3l, b3l);
        bf16x8 B0h = mkfrag(hi ? X0h : P0h, hi ? X1h : P1h,
                            hi ? a2h : X0h, hi ? a3h : X1h);
        bf16x8 B0l = mkfrag(hi ? X0l : P0l, hi ? X1l : P1l,
                            hi ? a2l : X0l, hi ? a3l : X1l);
        bf16x8 B1c = mkfrag(b2h, b2l, b2h, 0);

        // ---- L1: 3-chain + independent tail ----
        __builtin_amdgcn_s_setprio(1);
        f32x16 accA = mf(A1t0l, B0h, mf(A1t0h, B0l, mf(A1t0h, B0h, cb1)));
        f32x16 accB = mf(A1c, B1c, z);
        __builtin_amdgcn_s_setprio(0);
        f32x16 h1v;
#pragma unroll
        for (int i = 0; i < 16; ++i) h1v[i] = fmaxf(accA[i] + accB[i], 0.0f);

        // ---- L2: two independent 3-chains ----
        bf16x8 C0h, C0l, C1h, C1l;
        hfrag(h1v, C0h, C0l, C1h, C1l);
        __builtin_amdgcn_s_setprio(1);
        f32x16 a2A = mf(A2l0, C0h, mf(A2h0, C0l, mf(A2h0, C0h, cb2)));
        f32x16 a2B = mf(A2l1, C1h, mf(A2h1, C1l, mf(A2h1, C1h, z)));
        __builtin_amdgcn_s_setprio(0);
        f32x16 h2v;
#pragma unroll
        for (int i = 0; i < 16; ++i) h2v[i] = fmaxf(a2A[i] + a2B[i], 0.0f);

        // ---- L3 + residual: two independent 3-chains (C = lat + b3, z) ----
        bf16x8 D0h, D0l, D1h, D1l;
        hfrag(h2v, D0h, D0l, D1h, D1l);
        f32x16 c3;
#pragma unroll
        for (int i = 0; i < 16; ++i) c3[i] = lat[i] + cb3[i];
        __builtin_amdgcn_s_setprio(1);
        f32x16 nlA = mf(A3l0, D0h, mf(A3h0, D0l, mf(A3h0, D0h, c3)));
        f32x16 nlB = mf(A3l1, D1h, mf(A3h1, D1l, mf(A3h1, D1h, z)));
        __builtin_amdgcn_s_setprio(0);
#pragma unroll
        for (int i = 0; i < 16; ++i) lat[i] = nlA[i] + nlB[i];

        // ---- store out[r][t][:] ----
        float* ob = outr + (size_t)t * LL;
        const int o0 = hi ? 4 : 0;
        *reinterpret_cast<float2*>(ob + o0)     = make_float2(lat[0], lat[1]);
        *reinterpret_cast<float2*>(ob + o0 + 2) = make_float2(lat[2], lat[3]);
        *reinterpret_cast<float2*>(ob + (hi ? 12 : 8)) = make_float2(lat[4], lat[5]);
        if (!hi)
            *reinterpret_cast<float2*>(ob + 10) = make_float2(lat[6], lat[7]);

        ph = phn;
    }
}

extern "C" void kernel_launch(void* const* d_in, const int* in_sizes, int n_in,
                              void* d_out, int out_size, void* d_ws, size_t ws_size,
                              hipStream_t stream) {
    const float* phys    = (const float*)d_in[0];
    const float* latents = (const float*)d_in[1];
    const float* W1      = (const float*)d_in[2];
    const float* b1      = (const float*)d_in[3];
    const float* W2      = (const float*)d_in[4];
    const float* b2      = (const float*)d_in[5];
    const float* W3      = (const float*)d_in[6];
    const float* b3      = (const float*)d_in[7];
    float* out = (float*)d_out;

    const int threads = 256;             // 4 waves x 32 rows = 128 rows/block
    const int blocks = BB / 128;         // 512 blocks -> 2 waves/SIMD
    emulator_kernel<<<blocks, threads, 0, stream>>>(
        phys, latents, W1, b1, W2, b2, W3, b3, out);
}

// Round 14
// 593.171 us; speedup vs baseline: 6.7426x; 1.0122x over previous
//
#include <hip/hip_runtime.h>

// Recurrent MLP emulator: B=65536 rows, T=256 steps, MLP 18->32->32->14.
// 32x32x16 MFMA, split-bf16 fp32 emulation, permlane32_swap regrouping.
// R14 vs R13 (600us): output stores batched through per-wave LDS.
//   - WRITE_SIZE was 1.37x ideal + ~190MB RMW fetch: 56B/step scattered
//     float2 stores straddle 64B sectors -> partial-sector writes.
//   - Now: per-step ds_write to a wave-private LDS row buffer; every 8 steps
//     flush 448B/row contiguous (14x dwordx4 per lane) -> full sectors.
//   - VALU trims: cb3 folded into L3 B-chain C-input (kills c3 adds);
//     lat[8..15] provably stay 0 -> update only lat[0..7].

#define BB 65536
#define TT 256
#define LL 14
#define HH 32
#define RSTRIDE 116   // LDS row stride in floats (112 data + 4 pad; 4-way banks)

typedef float f32x16 __attribute__((ext_vector_type(16)));
typedef __bf16 bf16x8 __attribute__((ext_vector_type(8)));
typedef __bf16 bf16x2 __attribute__((ext_vector_type(2)));
typedef int i32x2 __attribute__((ext_vector_type(2)));

static __device__ __forceinline__ unsigned packbf(float a, float b) {
    bf16x2 p;
    p[0] = (__bf16)a;
    p[1] = (__bf16)b;
    return __builtin_bit_cast(unsigned, p);
}

static __device__ __forceinline__ void split2(float v0, float v1,
                                              unsigned& hw, unsigned& lw) {
    const __bf16 h0 = (__bf16)v0, h1 = (__bf16)v1;
    hw = packbf(v0, v1);
    const float l0 = v0 - (float)h0;
    const float l1 = v1 - (float)h1;
    lw = packbf(l0, l1);
}

static __device__ __forceinline__ bf16x8 mkfrag(unsigned w0, unsigned w1,
                                                unsigned w2, unsigned w3) {
    union { unsigned u[4]; bf16x8 v; } x;
    x.u[0] = w0; x.u[1] = w1; x.u[2] = w2; x.u[3] = w3;
    return x.v;
}

static __device__ __forceinline__ f32x16 mf(bf16x8 a, bf16x8 b, f32x16 c) {
    return __builtin_amdgcn_mfma_f32_32x32x16_bf16(a, b, c, 0, 0, 0);
}

#if __has_builtin(__builtin_amdgcn_permlane32_swap)
static __device__ __forceinline__ void xswap(unsigned a, unsigned b,
                                             unsigned& a_out, unsigned& b_out) {
    i32x2 r = __builtin_amdgcn_permlane32_swap((int)a, (int)b, false, false);
    a_out = (unsigned)r[0];
    b_out = (unsigned)r[1];
}
#else
static __device__ __forceinline__ void xswap(unsigned a, unsigned b,
                                             unsigned& a_out, unsigned& b_out) {
    const int lane = threadIdx.x & 63;
    const int idx = (lane ^ 32) << 2;
    unsigned sa = (unsigned)__builtin_amdgcn_ds_bpermute(idx, (int)a);
    unsigned sb = (unsigned)__builtin_amdgcn_ds_bpermute(idx, (int)b);
    const bool hi = lane >= 32;
    a_out = hi ? sb : a;
    b_out = hi ? b : sa;
}
#endif

static __device__ __forceinline__ void hfrag(const f32x16& h,
                                             bf16x8& B0h, bf16x8& B0l,
                                             bf16x8& B1h, bf16x8& B1l) {
    unsigned Wh[8], Wl[8];
#pragma unroll
    for (int p = 0; p < 8; ++p) split2(h[2 * p], h[2 * p + 1], Wh[p], Wl[p]);
    unsigned a02h, b02h, a02l, b02l, a13h, b13h, a13l, b13l;
    xswap(Wh[0], Wh[2], a02h, b02h); xswap(Wl[0], Wl[2], a02l, b02l);
    xswap(Wh[1], Wh[3], a13h, b13h); xswap(Wl[1], Wl[3], a13l, b13l);
    B0h = mkfrag(a02h, a13h, b02h, b13h);
    B0l = mkfrag(a02l, a13l, b02l, b13l);
    unsigned a46h, b46h, a46l, b46l, a57h, b57h, a57l, b57l;
    xswap(Wh[4], Wh[6], a46h, b46h); xswap(Wl[4], Wl[6], a46l, b46l);
    xswap(Wh[5], Wh[7], a57h, b57h); xswap(Wl[5], Wl[7], a57l, b57l);
    B1h = mkfrag(a46h, a57h, b46h, b57h);
    B1l = mkfrag(a46l, a57l, b46l, b57l);
}

__global__ __launch_bounds__(256, 2)
void emulator_kernel(const float* __restrict__ phys,
                     const float* __restrict__ latents,
                     const float* __restrict__ W1g,
                     const float* __restrict__ b1g,
                     const float* __restrict__ W2g,
                     const float* __restrict__ b2g,
                     const float* __restrict__ W3g,
                     const float* __restrict__ b3g,
                     float* __restrict__ out) {
    __shared__ float lds[4 * 32 * RSTRIDE];   // 59392 B, wave-private slices

    const int tid = threadIdx.x;
    const int lane = tid & 63;
    const int wv = tid >> 6;
    const int c = lane & 31;
    const bool hi = lane >= 32;
    const int kb = hi ? 8 : 0;
    const int r = blockIdx.x * 128 + wv * 32 + c;

    // ---- pinned A-frags (W^T tiles, bf16 hi/lo) ----
    bf16x8 A1t0h, A1t0l, A1c;
    {
        unsigned hw[4], lw[4];
#pragma unroll
        for (int w = 0; w < 4; ++w) {
            const int k0 = kb + 2 * w;
            split2(W1g[k0 * HH + c], W1g[(k0 + 1) * HH + c], hw[w], lw[w]);
        }
        A1t0h = mkfrag(hw[0], hw[1], hw[2], hw[3]);
        A1t0l = mkfrag(lw[0], lw[1], lw[2], lw[3]);
        unsigned whp, wlp;
        split2(W1g[16 * HH + c], W1g[17 * HH + c], whp, wlp);
        A1c = hi ? mkfrag(0, 0, 0, 0) : mkfrag(whp, whp, wlp, 0);
    }
    bf16x8 A2h0, A2l0, A2h1, A2l1, A3h0, A3l0, A3h1, A3l1;
    {
        unsigned hw[4], lw[4];
#pragma unroll
        for (int w = 0; w < 4; ++w) {
            const int k0 = kb + 2 * w;
            split2(W2g[k0 * HH + c], W2g[(k0 + 1) * HH + c], hw[w], lw[w]);
        }
        A2h0 = mkfrag(hw[0], hw[1], hw[2], hw[3]);
        A2l0 = mkfrag(lw[0], lw[1], lw[2], lw[3]);
#pragma unroll
        for (int w = 0; w < 4; ++w) {
            const int k0 = 16 + kb + 2 * w;
            split2(W2g[k0 * HH + c], W2g[(k0 + 1) * HH + c], hw[w], lw[w]);
        }
        A2h1 = mkfrag(hw[0], hw[1], hw[2], hw[3]);
        A2l1 = mkfrag(lw[0], lw[1], lw[2], lw[3]);
#pragma unroll
        for (int w = 0; w < 4; ++w) {
            const int k0 = kb + 2 * w;
            const float e0 = (c < LL) ? W3g[k0 * LL + c] : 0.0f;
            const float e1 = (c < LL) ? W3g[(k0 + 1) * LL + c] : 0.0f;
            split2(e0, e1, hw[w], lw[w]);
        }
        A3h0 = mkfrag(hw[0], hw[1], hw[2], hw[3]);
        A3l0 = mkfrag(lw[0], lw[1], lw[2], lw[3]);
#pragma unroll
        for (int w = 0; w < 4; ++w) {
            const int k0 = 16 + kb + 2 * w;
            const float e0 = (c < LL) ? W3g[k0 * LL + c] : 0.0f;
            const float e1 = (c < LL) ? W3g[(k0 + 1) * LL + c] : 0.0f;
            split2(e0, e1, hw[w], lw[w]);
        }
        A3h1 = mkfrag(hw[0], hw[1], hw[2], hw[3]);
        A3l1 = mkfrag(lw[0], lw[1], lw[2], lw[3]);
    }

    // ---- bias C-frags (D-layout) + pinned zero C-frag ----
    f32x16 cb1, cb2, cb3, z;
#pragma unroll
    for (int rr = 0; rr < 16; ++rr) {
        const int row = (rr & 3) + 8 * (rr >> 2) + (hi ? 4 : 0);
        cb1[rr] = b1g[row];
        cb2[rr] = b2g[row];
        cb3[rr] = (row < LL) ? b3g[row] : 0.0f;
        z[rr] = 0.0f;
    }

    // ---- latent state in D-layout (regs 0-7 meaningful; 8-15 stay 0) ----
    f32x16 lat;
#pragma unroll
    for (int i = 0; i < 16; ++i) lat[i] = 0.0f;
    {
        const float* lrow = latents + (size_t)r * LL;
        const float2* p01 = reinterpret_cast<const float2*>(lrow + (hi ? 4 : 0));
        const float2 v0 = p01[0], v1 = p01[1];
        lat[0] = v0.x; lat[1] = v0.y; lat[2] = v1.x; lat[3] = v1.y;
        const float2 v2 = reinterpret_cast<const float2*>(lrow + (hi ? 12 : 8))[0];
        lat[4] = v2.x; lat[5] = v2.y;
        if (!hi) {
            const float2 v3 = reinterpret_cast<const float2*>(lrow + 10)[0];
            lat[6] = v3.x; lat[7] = v3.y;
        }
    }

    const float4* pv = reinterpret_cast<const float4*>(phys) + (size_t)r * TT;
    float4 ph = pv[0];
    float* outr = out + (size_t)r * TT * LL;

    // LDS staging pointers (wave-private; no barriers needed)
    float* wrow_base = lds + wv * 32 * RSTRIDE + c * RSTRIDE;
    const int halfsel = hi ? 1 : 0;
    const float4* fl_src = reinterpret_cast<const float4*>(
        lds + wv * 32 * RSTRIDE + c * RSTRIDE + halfsel * 56);

#pragma unroll 1
    for (int t = 0; t < TT; ++t) {
        asm volatile("" : "+v"(A1t0h), "+v"(A1t0l), "+v"(A1c),
                          "+v"(A2h0), "+v"(A2l0), "+v"(A2h1), "+v"(A2l1),
                          "+v"(A3h0), "+v"(A3l0), "+v"(A3h1), "+v"(A3l1),
                          "+v"(cb1), "+v"(cb2), "+v"(cb3), "+v"(z));

        const float4 phn = pv[(t < TT - 1) ? (t + 1) : t];

        // ---- L1 B-frags from x = [ph(4), lat(14)] ----
        unsigned X0h, X0l, X1h, X1l, X2h, X2l, X3h, X3l, P0h, P0l, P1h, P1l;
        split2(lat[0], lat[1], X0h, X0l);
        split2(lat[2], lat[3], X1h, X1l);
        split2(lat[4], lat[5], X2h, X2l);
        split2(lat[6], lat[7], X3h, X3l);
        split2(ph.x, ph.y, P0h, P0l);
        split2(ph.z, ph.w, P1h, P1l);
        unsigned a2h, b2h, a2l, b2l, a3h, b3h, a3l, b3l;
        xswap(X2h, X2h, a2h, b2h); xswap(X2l, X2l, a2l, b2l);
        xswap(X3h, X3h, a3h, b3h); xswap(X3l, X3l, a3l, b3l);
        bf16x8 B0h = mkfrag(hi ? X0h : P0h, hi ? X1h : P1h,
                            hi ? a2h : X0h, hi ? a3h : X1h);
        bf16x8 B0l = mkfrag(hi ? X0l : P0l, hi ? X1l : P1l,
                            hi ? a2l : X0l, hi ? a3l : X1l);
        bf16x8 B1c = mkfrag(b2h, b2l, b2h, 0);

        // ---- L1 ----
        __builtin_amdgcn_s_setprio(1);
        f32x16 accA = mf(A1t0l, B0h, mf(A1t0h, B0l, mf(A1t0h, B0h, cb1)));
        f32x16 accB = mf(A1c, B1c, z);
        __builtin_amdgcn_s_setprio(0);
        f32x16 h1v;
#pragma unroll
        for (int i = 0; i < 16; ++i) h1v[i] = fmaxf(accA[i] + accB[i], 0.0f);

        // ---- L2 ----
        bf16x8 C0h, C0l, C1h, C1l;
        hfrag(h1v, C0h, C0l, C1h, C1l);
        __builtin_amdgcn_s_setprio(1);
        f32x16 a2A = mf(A2l0, C0h, mf(A2h0, C0l, mf(A2h0, C0h, cb2)));
        f32x16 a2B = mf(A2l1, C1h, mf(A2h1, C1l, mf(A2h1, C1h, z)));
        __builtin_amdgcn_s_setprio(0);
        f32x16 h2v;
#pragma unroll
        for (int i = 0; i < 16; ++i) h2v[i] = fmaxf(a2A[i] + a2B[i], 0.0f);

        // ---- L3 + residual: chainA C = lat, chainB C = cb3 ----
        bf16x8 D0h, D0l, D1h, D1l;
        hfrag(h2v, D0h, D0l, D1h, D1l);
        __builtin_amdgcn_s_setprio(1);
        f32x16 nlA = mf(A3l0, D0h, mf(A3h0, D0l, mf(A3h0, D0h, lat)));
        f32x16 nlB = mf(A3l1, D1h, mf(A3h1, D1l, mf(A3h1, D1h, cb3)));
        __builtin_amdgcn_s_setprio(0);
#pragma unroll
        for (int i = 0; i < 8; ++i) lat[i] = nlA[i] + nlB[i];
        // lat[8..15] remain 0 (W3 rows >= 16 are zero-padded; cb3 there = 0)

        // ---- stage this step's 14 outputs into wave-private LDS ----
        {
            float* wr = wrow_base + (t & 7) * LL;
            if (!hi) {
                *reinterpret_cast<float2*>(wr + 0)  = make_float2(lat[0], lat[1]);
                *reinterpret_cast<float2*>(wr + 2)  = make_float2(lat[2], lat[3]);
                *reinterpret_cast<float2*>(wr + 8)  = make_float2(lat[4], lat[5]);
                *reinterpret_cast<float2*>(wr + 10) = make_float2(lat[6], lat[7]);
            } else {
                *reinterpret_cast<float2*>(wr + 4)  = make_float2(lat[0], lat[1]);
                *reinterpret_cast<float2*>(wr + 6)  = make_float2(lat[2], lat[3]);
                *reinterpret_cast<float2*>(wr + 12) = make_float2(lat[4], lat[5]);
            }
        }

        // ---- flush every 8 steps: 224B contiguous per lane, full sectors ----
        if ((t & 7) == 7) {
            float4* gdst = reinterpret_cast<float4*>(
                outr + (size_t)(t - 7 + 4 * halfsel) * LL);
#pragma unroll
            for (int q = 0; q < 14; ++q) gdst[q] = fl_src[q];
        }

        ph = phn;
    }
}

extern "C" void kernel_launch(void* const* d_in, const int* in_sizes, int n_in,
                              void* d_out, int out_size, void* d_ws, size_t ws_size,
                              hipStream_t stream) {
    const float* phys    = (const float*)d_in[0];
    const float* latents = (const float*)d_in[1];
    const float* W1      = (const float*)d_in[2];
    const float* b1      = (const float*)d_in[3];
    const float* W2      = (const float*)d_in[4];
    const float* b2      = (const float*)d_in[5];
    const float* W3      = (const float*)d_in[6];
    const float* b3      = (const float*)d_in[7];
    float* out = (float*)d_out;

    const int threads = 256;             // 4 waves x 32 rows = 128 rows/block
    const int blocks = BB / 128;         // 512 blocks -> 2 waves/SIMD
    emulator_kernel<<<blocks, threads, 0, stream>>>(
        phys, latents, W1, b1, W2, b2, W3, b3, out);
}

// Round 15
// 592.426 us; speedup vs baseline: 6.7511x; 1.0013x over previous
//
#include <hip/hip_runtime.h>

// Recurrent MLP emulator: B=65536 rows, T=256 steps, MLP 18->32->32->14.
// 32x32x16 MFMA, split-bf16 fp32 emulation, permlane32_swap regrouping.
// R15 vs R14 (593us; memory traffic fixed but dur flat -> issue-bound,
// ~830 VALU/wave-step vs ~300 static = AGPR<->VGPR round trips):
//  1. Bias/zero C-frags pinned in AGPRs ("+a") — MFMA C-input reads AGPR
//     natively; kills v_accvgpr_write bursts and frees 64 VGPRs of pressure.
//  2. L3 drops the A_hi*B_lo term (h2 lo-split removed): hfrag_hi = 8 pack
//     + 4 xswap; L3 chains 3->2 MFMAs. Increment-only precision cost ~2^-9.

#define BB 65536
#define TT 256
#define LL 14
#define HH 32
#define RSTRIDE 116   // LDS row stride in floats

typedef float f32x16 __attribute__((ext_vector_type(16)));
typedef __bf16 bf16x8 __attribute__((ext_vector_type(8)));
typedef __bf16 bf16x2 __attribute__((ext_vector_type(2)));
typedef int i32x2 __attribute__((ext_vector_type(2)));

static __device__ __forceinline__ unsigned packbf(float a, float b) {
    bf16x2 p;
    p[0] = (__bf16)a;
    p[1] = (__bf16)b;
    return __builtin_bit_cast(unsigned, p);
}

static __device__ __forceinline__ void split2(float v0, float v1,
                                              unsigned& hw, unsigned& lw) {
    const __bf16 h0 = (__bf16)v0, h1 = (__bf16)v1;
    hw = packbf(v0, v1);
    const float l0 = v0 - (float)h0;
    const float l1 = v1 - (float)h1;
    lw = packbf(l0, l1);
}

static __device__ __forceinline__ bf16x8 mkfrag(unsigned w0, unsigned w1,
                                                unsigned w2, unsigned w3) {
    union { unsigned u[4]; bf16x8 v; } x;
    x.u[0] = w0; x.u[1] = w1; x.u[2] = w2; x.u[3] = w3;
    return x.v;
}

static __device__ __forceinline__ f32x16 mf(bf16x8 a, bf16x8 b, f32x16 c) {
    return __builtin_amdgcn_mfma_f32_32x32x16_bf16(a, b, c, 0, 0, 0);
}

#if __has_builtin(__builtin_amdgcn_permlane32_swap)
static __device__ __forceinline__ void xswap(unsigned a, unsigned b,
                                             unsigned& a_out, unsigned& b_out) {
    i32x2 r = __builtin_amdgcn_permlane32_swap((int)a, (int)b, false, false);
    a_out = (unsigned)r[0];
    b_out = (unsigned)r[1];
}
#else
static __device__ __forceinline__ void xswap(unsigned a, unsigned b,
                                             unsigned& a_out, unsigned& b_out) {
    const int lane = threadIdx.x & 63;
    const int idx = (lane ^ 32) << 2;
    unsigned sa = (unsigned)__builtin_amdgcn_ds_bpermute(idx, (int)a);
    unsigned sb = (unsigned)__builtin_amdgcn_ds_bpermute(idx, (int)b);
    const bool hi = lane >= 32;
    a_out = hi ? sb : a;
    b_out = hi ? b : sa;
}
#endif

// Full hi/lo regroup (used for h1 -> L2 input).
static __device__ __forceinline__ void hfrag(const f32x16& h,
                                             bf16x8& B0h, bf16x8& B0l,
                                             bf16x8& B1h, bf16x8& B1l) {
    unsigned Wh[8], Wl[8];
#pragma unroll
    for (int p = 0; p < 8; ++p) split2(h[2 * p], h[2 * p + 1], Wh[p], Wl[p]);
    unsigned a02h, b02h, a02l, b02l, a13h, b13h, a13l, b13l;
    xswap(Wh[0], Wh[2], a02h, b02h); xswap(Wl[0], Wl[2], a02l, b02l);
    xswap(Wh[1], Wh[3], a13h, b13h); xswap(Wl[1], Wl[3], a13l, b13l);
    B0h = mkfrag(a02h, a13h, b02h, b13h);
    B0l = mkfrag(a02l, a13l, b02l, b13l);
    unsigned a46h, b46h, a46l, b46l, a57h, b57h, a57l, b57l;
    xswap(Wh[4], Wh[6], a46h, b46h); xswap(Wl[4], Wl[6], a46l, b46l);
    xswap(Wh[5], Wh[7], a57h, b57h); xswap(Wl[5], Wl[7], a57l, b57l);
    B1h = mkfrag(a46h, a57h, b46h, b57h);
    B1l = mkfrag(a46l, a57l, b46l, b57l);
}

// Hi-only regroup (used for h2 -> L3 input; lo term dropped).
static __device__ __forceinline__ void hfrag_hi(const f32x16& h,
                                                bf16x8& B0h, bf16x8& B1h) {
    unsigned Wh[8];
#pragma unroll
    for (int p = 0; p < 8; ++p) Wh[p] = packbf(h[2 * p], h[2 * p + 1]);
    unsigned a02h, b02h, a13h, b13h, a46h, b46h, a57h, b57h;
    xswap(Wh[0], Wh[2], a02h, b02h);
    xswap(Wh[1], Wh[3], a13h, b13h);
    xswap(Wh[4], Wh[6], a46h, b46h);
    xswap(Wh[5], Wh[7], a57h, b57h);
    B0h = mkfrag(a02h, a13h, b02h, b13h);
    B1h = mkfrag(a46h, a57h, b46h, b57h);
}

__global__ __launch_bounds__(256, 2)
void emulator_kernel(const float* __restrict__ phys,
                     const float* __restrict__ latents,
                     const float* __restrict__ W1g,
                     const float* __restrict__ b1g,
                     const float* __restrict__ W2g,
                     const float* __restrict__ b2g,
                     const float* __restrict__ W3g,
                     const float* __restrict__ b3g,
                     float* __restrict__ out) {
    __shared__ float lds[4 * 32 * RSTRIDE];

    const int tid = threadIdx.x;
    const int lane = tid & 63;
    const int wv = tid >> 6;
    const int c = lane & 31;
    const bool hi = lane >= 32;
    const int kb = hi ? 8 : 0;
    const int r = blockIdx.x * 128 + wv * 32 + c;

    // ---- pinned A-frags (W^T tiles, bf16 hi/lo) ----
    bf16x8 A1t0h, A1t0l, A1c;
    {
        unsigned hw[4], lw[4];
#pragma unroll
        for (int w = 0; w < 4; ++w) {
            const int k0 = kb + 2 * w;
            split2(W1g[k0 * HH + c], W1g[(k0 + 1) * HH + c], hw[w], lw[w]);
        }
        A1t0h = mkfrag(hw[0], hw[1], hw[2], hw[3]);
        A1t0l = mkfrag(lw[0], lw[1], lw[2], lw[3]);
        unsigned whp, wlp;
        split2(W1g[16 * HH + c], W1g[17 * HH + c], whp, wlp);
        A1c = hi ? mkfrag(0, 0, 0, 0) : mkfrag(whp, whp, wlp, 0);
    }
    bf16x8 A2h0, A2l0, A2h1, A2l1, A3h0, A3l0, A3h1, A3l1;
    {
        unsigned hw[4], lw[4];
#pragma unroll
        for (int w = 0; w < 4; ++w) {
            const int k0 = kb + 2 * w;
            split2(W2g[k0 * HH + c], W2g[(k0 + 1) * HH + c], hw[w], lw[w]);
        }
        A2h0 = mkfrag(hw[0], hw[1], hw[2], hw[3]);
        A2l0 = mkfrag(lw[0], lw[1], lw[2], lw[3]);
#pragma unroll
        for (int w = 0; w < 4; ++w) {
            const int k0 = 16 + kb + 2 * w;
            split2(W2g[k0 * HH + c], W2g[(k0 + 1) * HH + c], hw[w], lw[w]);
        }
        A2h1 = mkfrag(hw[0], hw[1], hw[2], hw[3]);
        A2l1 = mkfrag(lw[0], lw[1], lw[2], lw[3]);
#pragma unroll
        for (int w = 0; w < 4; ++w) {
            const int k0 = kb + 2 * w;
            const float e0 = (c < LL) ? W3g[k0 * LL + c] : 0.0f;
            const float e1 = (c < LL) ? W3g[(k0 + 1) * LL + c] : 0.0f;
            split2(e0, e1, hw[w], lw[w]);
        }
        A3h0 = mkfrag(hw[0], hw[1], hw[2], hw[3]);
        A3l0 = mkfrag(lw[0], lw[1], lw[2], lw[3]);
#pragma unroll
        for (int w = 0; w < 4; ++w) {
            const int k0 = 16 + kb + 2 * w;
            const float e0 = (c < LL) ? W3g[k0 * LL + c] : 0.0f;
            const float e1 = (c < LL) ? W3g[(k0 + 1) * LL + c] : 0.0f;
            split2(e0, e1, hw[w], lw[w]);
        }
        A3h1 = mkfrag(hw[0], hw[1], hw[2], hw[3]);
        A3l1 = mkfrag(lw[0], lw[1], lw[2], lw[3]);
    }

    // ---- bias C-frags (D-layout) + zero C-frag -> pinned in AGPRs ----
    f32x16 cb1, cb2, cb3, z;
#pragma unroll
    for (int rr = 0; rr < 16; ++rr) {
        const int row = (rr & 3) + 8 * (rr >> 2) + (hi ? 4 : 0);
        cb1[rr] = b1g[row];
        cb2[rr] = b2g[row];
        cb3[rr] = (row < LL) ? b3g[row] : 0.0f;
        z[rr] = 0.0f;
    }

    // ---- latent state in D-layout (regs 0-7 meaningful; 8-15 stay 0) ----
    f32x16 lat;
#pragma unroll
    for (int i = 0; i < 16; ++i) lat[i] = 0.0f;
    {
        const float* lrow = latents + (size_t)r * LL;
        const float2* p01 = reinterpret_cast<const float2*>(lrow + (hi ? 4 : 0));
        const float2 v0 = p01[0], v1 = p01[1];
        lat[0] = v0.x; lat[1] = v0.y; lat[2] = v1.x; lat[3] = v1.y;
        const float2 v2 = reinterpret_cast<const float2*>(lrow + (hi ? 12 : 8))[0];
        lat[4] = v2.x; lat[5] = v2.y;
        if (!hi) {
            const float2 v3 = reinterpret_cast<const float2*>(lrow + 10)[0];
            lat[6] = v3.x; lat[7] = v3.y;
        }
    }

    const float4* pv = reinterpret_cast<const float4*>(phys) + (size_t)r * TT;
    float4 ph = pv[0];
    float* outr = out + (size_t)r * TT * LL;

    float* wrow_base = lds + wv * 32 * RSTRIDE + c * RSTRIDE;
    const int halfsel = hi ? 1 : 0;
    const float4* fl_src = reinterpret_cast<const float4*>(
        lds + wv * 32 * RSTRIDE + c * RSTRIDE + halfsel * 56);

#pragma unroll 1
    for (int t = 0; t < TT; ++t) {
        // Weights pinned in VGPRs; bias/zero C-frags pinned in AGPRs
        // (MFMA reads C natively from AGPR -> no accvgpr_write bursts).
        asm volatile("" : "+v"(A1t0h), "+v"(A1t0l), "+v"(A1c),
                          "+v"(A2h0), "+v"(A2l0), "+v"(A2h1), "+v"(A2l1),
                          "+v"(A3h0), "+v"(A3l0), "+v"(A3h1), "+v"(A3l1));
        asm volatile("" : "+a"(cb1), "+a"(cb2), "+a"(cb3), "+a"(z));

        const float4 phn = pv[(t < TT - 1) ? (t + 1) : t];

        // ---- L1 B-frags from x = [ph(4), lat(14)] ----
        unsigned X0h, X0l, X1h, X1l, X2h, X2l, X3h, X3l, P0h, P0l, P1h, P1l;
        split2(lat[0], lat[1], X0h, X0l);
        split2(lat[2], lat[3], X1h, X1l);
        split2(lat[4], lat[5], X2h, X2l);
        split2(lat[6], lat[7], X3h, X3l);
        split2(ph.x, ph.y, P0h, P0l);
        split2(ph.z, ph.w, P1h, P1l);
        unsigned a2h, b2h, a2l, b2l, a3h, b3h, a3l, b3l;
        xswap(X2h, X2h, a2h, b2h); xswap(X2l, X2l, a2l, b2l);
        xswap(X3h, X3h, a3h, b3h); xswap(X3l, X3l, a3l, b3l);
        bf16x8 B0h = mkfrag(hi ? X0h : P0h, hi ? X1h : P1h,
                            hi ? a2h : X0h, hi ? a3h : X1h);
        bf16x8 B0l = mkfrag(hi ? X0l : P0l, hi ? X1l : P1l,
                            hi ? a2l : X0l, hi ? a3l : X1l);
        bf16x8 B1c = mkfrag(b2h, b2l, b2h, 0);

        // ---- L1 ----
        __builtin_amdgcn_s_setprio(1);
        f32x16 accA = mf(A1t0l, B0h, mf(A1t0h, B0l, mf(A1t0h, B0h, cb1)));
        f32x16 accB = mf(A1c, B1c, z);
        __builtin_amdgcn_s_setprio(0);
        f32x16 h1v;
#pragma unroll
        for (int i = 0; i < 16; ++i) h1v[i] = fmaxf(accA[i] + accB[i], 0.0f);

        // ---- L2 (full hi/lo) ----
        bf16x8 C0h, C0l, C1h, C1l;
        hfrag(h1v, C0h, C0l, C1h, C1l);
        __builtin_amdgcn_s_setprio(1);
        f32x16 a2A = mf(A2l0, C0h, mf(A2h0, C0l, mf(A2h0, C0h, cb2)));
        f32x16 a2B = mf(A2l1, C1h, mf(A2h1, C1l, mf(A2h1, C1h, z)));
        __builtin_amdgcn_s_setprio(0);
        f32x16 h2v;
#pragma unroll
        for (int i = 0; i < 16; ++i) h2v[i] = fmaxf(a2A[i] + a2B[i], 0.0f);

        // ---- L3 + residual (hi-only h2; chains of 2) ----
        bf16x8 D0h, D1h;
        hfrag_hi(h2v, D0h, D1h);
        __builtin_amdgcn_s_setprio(1);
        f32x16 nlA = mf(A3l0, D0h, mf(A3h0, D0h, lat));
        f32x16 nlB = mf(A3l1, D1h, mf(A3h1, D1h, cb3));
        __builtin_amdgcn_s_setprio(0);
#pragma unroll
        for (int i = 0; i < 8; ++i) lat[i] = nlA[i] + nlB[i];
        // lat[8..15] remain 0 (W3 zero-padded rows; cb3 zero there)

        // ---- stage this step's 14 outputs into wave-private LDS ----
        {
            float* wr = wrow_base + (t & 7) * LL;
            if (!hi) {
                *reinterpret_cast<float2*>(wr + 0)  = make_float2(lat[0], lat[1]);
                *reinterpret_cast<float2*>(wr + 2)  = make_float2(lat[2], lat[3]);
                *reinterpret_cast<float2*>(wr + 8)  = make_float2(lat[4], lat[5]);
                *reinterpret_cast<float2*>(wr + 10) = make_float2(lat[6], lat[7]);
            } else {
                *reinterpret_cast<float2*>(wr + 4)  = make_float2(lat[0], lat[1]);
                *reinterpret_cast<float2*>(wr + 6)  = make_float2(lat[2], lat[3]);
                *reinterpret_cast<float2*>(wr + 12) = make_float2(lat[4], lat[5]);
            }
        }

        // ---- flush every 8 steps: 224B contiguous per lane ----
        if ((t & 7) == 7) {
            float4* gdst = reinterpret_cast<float4*>(
                outr + (size_t)(t - 7 + 4 * halfsel) * LL);
#pragma unroll
            for (int q = 0; q < 14; ++q) gdst[q] = fl_src[q];
        }

        ph = phn;
    }
}

extern "C" void kernel_launch(void* const* d_in, const int* in_sizes, int n_in,
                              void* d_out, int out_size, void* d_ws, size_t ws_size,
                              hipStream_t stream) {
    const float* phys    = (const float*)d_in[0];
    const float* latents = (const float*)d_in[1];
    const float* W1      = (const float*)d_in[2];
    const float* b1      = (const float*)d_in[3];
    const float* W2      = (const float*)d_in[4];
    const float* b2      = (const float*)d_in[5];
    const float* W3      = (const float*)d_in[6];
    const float* b3      = (const float*)d_in[7];
    float* out = (float*)d_out;

    const int threads = 256;             // 4 waves x 32 rows = 128 rows/block
    const int blocks = BB / 128;         // 512 blocks -> 2 waves/SIMD
    emulator_kernel<<<blocks, threads, 0, stream>>>(
        phys, latents, W1, b1, W2, b2, W3, b3, out);
}

// Round 17
// 572.377 us; speedup vs baseline: 6.9875x; 1.0350x over previous
//
#include <hip/hip_runtime.h>

// Recurrent MLP emulator: B=65536 rows, T=256 steps, MLP 18->32->32->14.
// 32x32x16 MFMA, mixed-precision split-bf16, permlane32_swap regrouping.
// R17 vs R16 (FAILED absmax 1.36e7 > 8.7e6 after dropping 3 lo-terms):
//  Restore the A-side lo terms (W2-lo, W3-lo; +4 MFMAs, depth-2 chains).
//  Keep B-side h-lo terms dropped -> hfrag_hi stays at both boundaries
//  (the VALU win, ~72 ops/step). Dropped now: {h1-lo*W2hi, h2-lo*W3hi}.
//  Calibration: h2-lo = +0.8e6 (R15); h1-lo est ~3.6e6 (R16 attribution)
//  -> predicted absmax ~6.5e6 < 8.7e6.

#define BB 65536
#define TT 256
#define LL 14
#define HH 32
#define RSTRIDE 116   // LDS row stride in floats

typedef float f32x16 __attribute__((ext_vector_type(16)));
typedef __bf16 bf16x8 __attribute__((ext_vector_type(8)));
typedef __bf16 bf16x2 __attribute__((ext_vector_type(2)));
typedef int i32x2 __attribute__((ext_vector_type(2)));

static __device__ __forceinline__ unsigned packbf(float a, float b) {
    bf16x2 p;
    p[0] = (__bf16)a;
    p[1] = (__bf16)b;
    return __builtin_bit_cast(unsigned, p);
}

static __device__ __forceinline__ void split2(float v0, float v1,
                                              unsigned& hw, unsigned& lw) {
    const __bf16 h0 = (__bf16)v0, h1 = (__bf16)v1;
    hw = packbf(v0, v1);
    const float l0 = v0 - (float)h0;
    const float l1 = v1 - (float)h1;
    lw = packbf(l0, l1);
}

static __device__ __forceinline__ bf16x8 mkfrag(unsigned w0, unsigned w1,
                                                unsigned w2, unsigned w3) {
    union { unsigned u[4]; bf16x8 v; } x;
    x.u[0] = w0; x.u[1] = w1; x.u[2] = w2; x.u[3] = w3;
    return x.v;
}

static __device__ __forceinline__ f32x16 mf(bf16x8 a, bf16x8 b, f32x16 c) {
    return __builtin_amdgcn_mfma_f32_32x32x16_bf16(a, b, c, 0, 0, 0);
}

#if __has_builtin(__builtin_amdgcn_permlane32_swap)
static __device__ __forceinline__ void xswap(unsigned a, unsigned b,
                                             unsigned& a_out, unsigned& b_out) {
    i32x2 r = __builtin_amdgcn_permlane32_swap((int)a, (int)b, false, false);
    a_out = (unsigned)r[0];
    b_out = (unsigned)r[1];
}
#else
static __device__ __forceinline__ void xswap(unsigned a, unsigned b,
                                             unsigned& a_out, unsigned& b_out) {
    const int lane = threadIdx.x & 63;
    const int idx = (lane ^ 32) << 2;
    unsigned sa = (unsigned)__builtin_amdgcn_ds_bpermute(idx, (int)a);
    unsigned sb = (unsigned)__builtin_amdgcn_ds_bpermute(idx, (int)b);
    const bool hi = lane >= 32;
    a_out = hi ? sb : a;
    b_out = hi ? b : sa;
}
#endif

// Hi-only regroup: D-layout 32-vector -> two K-tile B-frags (bf16, RTNE).
static __device__ __forceinline__ void hfrag_hi(const f32x16& h,
                                                bf16x8& B0h, bf16x8& B1h) {
    unsigned Wh[8];
#pragma unroll
    for (int p = 0; p < 8; ++p) Wh[p] = packbf(h[2 * p], h[2 * p + 1]);
    unsigned a02h, b02h, a13h, b13h, a46h, b46h, a57h, b57h;
    xswap(Wh[0], Wh[2], a02h, b02h);
    xswap(Wh[1], Wh[3], a13h, b13h);
    xswap(Wh[4], Wh[6], a46h, b46h);
    xswap(Wh[5], Wh[7], a57h, b57h);
    B0h = mkfrag(a02h, a13h, b02h, b13h);
    B1h = mkfrag(a46h, a57h, b46h, b57h);
}

__global__ __launch_bounds__(256, 2)
void emulator_kernel(const float* __restrict__ phys,
                     const float* __restrict__ latents,
                     const float* __restrict__ W1g,
                     const float* __restrict__ b1g,
                     const float* __restrict__ W2g,
                     const float* __restrict__ b2g,
                     const float* __restrict__ W3g,
                     const float* __restrict__ b3g,
                     float* __restrict__ out) {
    __shared__ float lds[4 * 32 * RSTRIDE];

    const int tid = threadIdx.x;
    const int lane = tid & 63;
    const int wv = tid >> 6;
    const int c = lane & 31;
    const bool hi = lane >= 32;
    const int kb = hi ? 8 : 0;
    const int r = blockIdx.x * 128 + wv * 32 + c;

    // ---- pinned A-frags: W1 hi+lo; W2/W3 hi+lo (restored A-side terms) ----
    bf16x8 A1t0h, A1t0l, A1c;
    {
        unsigned hw[4], lw[4];
#pragma unroll
        for (int w = 0; w < 4; ++w) {
            const int k0 = kb + 2 * w;
            split2(W1g[k0 * HH + c], W1g[(k0 + 1) * HH + c], hw[w], lw[w]);
        }
        A1t0h = mkfrag(hw[0], hw[1], hw[2], hw[3]);
        A1t0l = mkfrag(lw[0], lw[1], lw[2], lw[3]);
        unsigned whp, wlp;
        split2(W1g[16 * HH + c], W1g[17 * HH + c], whp, wlp);
        A1c = hi ? mkfrag(0, 0, 0, 0) : mkfrag(whp, whp, wlp, 0);
    }
    bf16x8 A2h0, A2l0, A2h1, A2l1, A3h0, A3l0, A3h1, A3l1;
    {
        unsigned hw[4], lw[4];
#pragma unroll
        for (int w = 0; w < 4; ++w) {
            const int k0 = kb + 2 * w;
            split2(W2g[k0 * HH + c], W2g[(k0 + 1) * HH + c], hw[w], lw[w]);
        }
        A2h0 = mkfrag(hw[0], hw[1], hw[2], hw[3]);
        A2l0 = mkfrag(lw[0], lw[1], lw[2], lw[3]);
#pragma unroll
        for (int w = 0; w < 4; ++w) {
            const int k0 = 16 + kb + 2 * w;
            split2(W2g[k0 * HH + c], W2g[(k0 + 1) * HH + c], hw[w], lw[w]);
        }
        A2h1 = mkfrag(hw[0], hw[1], hw[2], hw[3]);
        A2l1 = mkfrag(lw[0], lw[1], lw[2], lw[3]);
#pragma unroll
        for (int w = 0; w < 4; ++w) {
            const int k0 = kb + 2 * w;
            const float e0 = (c < LL) ? W3g[k0 * LL + c] : 0.0f;
            const float e1 = (c < LL) ? W3g[(k0 + 1) * LL + c] : 0.0f;
            split2(e0, e1, hw[w], lw[w]);
        }
        A3h0 = mkfrag(hw[0], hw[1], hw[2], hw[3]);
        A3l0 = mkfrag(lw[0], lw[1], lw[2], lw[3]);
#pragma unroll
        for (int w = 0; w < 4; ++w) {
            const int k0 = 16 + kb + 2 * w;
            const float e0 = (c < LL) ? W3g[k0 * LL + c] : 0.0f;
            const float e1 = (c < LL) ? W3g[(k0 + 1) * LL + c] : 0.0f;
            split2(e0, e1, hw[w], lw[w]);
        }
        A3h1 = mkfrag(hw[0], hw[1], hw[2], hw[3]);
        A3l1 = mkfrag(lw[0], lw[1], lw[2], lw[3]);
    }

    // ---- bias C-frags (D-layout) + zero C-frag -> pinned in AGPRs ----
    f32x16 cb1, cb2, cb3, z;
#pragma unroll
    for (int rr = 0; rr < 16; ++rr) {
        const int row = (rr & 3) + 8 * (rr >> 2) + (hi ? 4 : 0);
        cb1[rr] = b1g[row];
        cb2[rr] = b2g[row];
        cb3[rr] = (row < LL) ? b3g[row] : 0.0f;
        z[rr] = 0.0f;
    }

    // ---- latent state in D-layout (regs 0-7 meaningful; 8-15 stay 0) ----
    f32x16 lat;
#pragma unroll
    for (int i = 0; i < 16; ++i) lat[i] = 0.0f;
    {
        const float* lrow = latents + (size_t)r * LL;
        const float2* p01 = reinterpret_cast<const float2*>(lrow + (hi ? 4 : 0));
        const float2 v0 = p01[0], v1 = p01[1];
        lat[0] = v0.x; lat[1] = v0.y; lat[2] = v1.x; lat[3] = v1.y;
        const float2 v2 = reinterpret_cast<const float2*>(lrow + (hi ? 12 : 8))[0];
        lat[4] = v2.x; lat[5] = v2.y;
        if (!hi) {
            const float2 v3 = reinterpret_cast<const float2*>(lrow + 10)[0];
            lat[6] = v3.x; lat[7] = v3.y;
        }
    }

    const float4* pv = reinterpret_cast<const float4*>(phys) + (size_t)r * TT;
    float4 ph = pv[0];
    float* outr = out + (size_t)r * TT * LL;

    float* wrow_base = lds + wv * 32 * RSTRIDE + c * RSTRIDE;
    const int halfsel = hi ? 1 : 0;
    const float4* fl_src = reinterpret_cast<const float4*>(
        lds + wv * 32 * RSTRIDE + c * RSTRIDE + halfsel * 56);

#pragma unroll 1
    for (int t = 0; t < TT; ++t) {
        asm volatile("" : "+v"(A1t0h), "+v"(A1t0l), "+v"(A1c),
                          "+v"(A2h0), "+v"(A2l0), "+v"(A2h1), "+v"(A2l1),
                          "+v"(A3h0), "+v"(A3l0), "+v"(A3h1), "+v"(A3l1));
        asm volatile("" : "+a"(cb1), "+a"(cb2), "+a"(cb3), "+a"(z));

        const float4 phn = pv[(t < TT - 1) ? (t + 1) : t];

        // ---- L1 B-frags from x = [ph(4), lat(14)]; lat keeps hi+lo ----
        unsigned X0h, X0l, X1h, X1l, X2h, X2l, X3h, X3l, P0h, P0l, P1h, P1l;
        split2(lat[0], lat[1], X0h, X0l);
        split2(lat[2], lat[3], X1h, X1l);
        split2(lat[4], lat[5], X2h, X2l);
        split2(lat[6], lat[7], X3h, X3l);
        split2(ph.x, ph.y, P0h, P0l);
        split2(ph.z, ph.w, P1h, P1l);
        unsigned a2h, b2h, a2l, b2l, a3h, b3h, a3l, b3l;
        xswap(X2h, X2h, a2h, b2h); xswap(X2l, X2l, a2l, b2l);
        xswap(X3h, X3h, a3h, b3h); xswap(X3l, X3l, a3l, b3l);
        bf16x8 B0h = mkfrag(hi ? X0h : P0h, hi ? X1h : P1h,
                            hi ? a2h : X0h, hi ? a3h : X1h);
        bf16x8 B0l = mkfrag(hi ? X0l : P0l, hi ? X1l : P1l,
                            hi ? a2l : X0l, hi ? a3l : X1l);
        bf16x8 B1c = mkfrag(b2h, b2l, b2h, 0);

        // ---- L1: Ah*Bh + Ah*Bl + Al*Bh (3-chain) + tail (1) ----
        __builtin_amdgcn_s_setprio(1);
        f32x16 accA = mf(A1t0l, B0h, mf(A1t0h, B0l, mf(A1t0h, B0h, cb1)));
        f32x16 accB = mf(A1c, B1c, z);
        __builtin_amdgcn_s_setprio(0);
        f32x16 h1v;
#pragma unroll
        for (int i = 0; i < 16; ++i) h1v[i] = fmaxf(accA[i] + accB[i], 0.0f);

        // ---- L2: h1-hi only; W2 hi+lo -> two depth-2 chains ----
        bf16x8 C0h, C1h;
        hfrag_hi(h1v, C0h, C1h);
        __builtin_amdgcn_s_setprio(1);
        f32x16 a2A = mf(A2l0, C0h, mf(A2h0, C0h, cb2));
        f32x16 a2B = mf(A2l1, C1h, mf(A2h1, C1h, z));
        __builtin_amdgcn_s_setprio(0);
        f32x16 h2v;
#pragma unroll
        for (int i = 0; i < 16; ++i) h2v[i] = fmaxf(a2A[i] + a2B[i], 0.0f);

        // ---- L3 + residual: h2-hi only; W3 hi+lo -> two depth-2 chains ----
        bf16x8 D0h, D1h;
        hfrag_hi(h2v, D0h, D1h);
        __builtin_amdgcn_s_setprio(1);
        f32x16 nlA = mf(A3l0, D0h, mf(A3h0, D0h, lat));
        f32x16 nlB = mf(A3l1, D1h, mf(A3h1, D1h, cb3));
        __builtin_amdgcn_s_setprio(0);
#pragma unroll
        for (int i = 0; i < 8; ++i) lat[i] = nlA[i] + nlB[i];
        // lat[8..15] remain 0 (W3 zero-padded rows; cb3 zero there)

        // ---- stage this step's 14 outputs into wave-private LDS ----
        {
            float* wr = wrow_base + (t & 7) * LL;
            if (!hi) {
                *reinterpret_cast<float2*>(wr + 0)  = make_float2(lat[0], lat[1]);
                *reinterpret_cast<float2*>(wr + 2)  = make_float2(lat[2], lat[3]);
                *reinterpret_cast<float2*>(wr + 8)  = make_float2(lat[4], lat[5]);
                *reinterpret_cast<float2*>(wr + 10) = make_float2(lat[6], lat[7]);
            } else {
                *reinterpret_cast<float2*>(wr + 4)  = make_float2(lat[0], lat[1]);
                *reinterpret_cast<float2*>(wr + 6)  = make_float2(lat[2], lat[3]);
                *reinterpret_cast<float2*>(wr + 12) = make_float2(lat[4], lat[5]);
            }
        }

        // ---- flush every 8 steps: 224B contiguous per lane ----
        if ((t & 7) == 7) {
            float4* gdst = reinterpret_cast<float4*>(
                outr + (size_t)(t - 7 + 4 * halfsel) * LL);
#pragma unroll
            for (int q = 0; q < 14; ++q) gdst[q] = fl_src[q];
        }

        ph = phn;
    }
}

extern "C" void kernel_launch(void* const* d_in, const int* in_sizes, int n_in,
                              void* d_out, int out_size, void* d_ws, size_t ws_size,
                              hipStream_t stream) {
    const float* phys    = (const float*)d_in[0];
    const float* latents = (const float*)d_in[1];
    const float* W1      = (const float*)d_in[2];
    const float* b1      = (const float*)d_in[3];
    const float* W2      = (const float*)d_in[4];
    const float* b2      = (const float*)d_in[5];
    const float* W3      = (const float*)d_in[6];
    const float* b3      = (const float*)d_in[7];
    float* out = (float*)d_out;

    const int threads = 256;             // 4 waves x 32 rows = 128 rows/block
    const int blocks = BB / 128;         // 512 blocks -> 2 waves/SIMD
    emulator_kernel<<<blocks, threads, 0, stream>>>(
        phys, latents, W1, b1, W2, b2, W3, b3, out);
}

// Round 18
// 568.176 us; speedup vs baseline: 7.0392x; 1.0074x over previous
//
#include <hip/hip_runtime.h>

// Recurrent MLP emulator: B=65536 rows, T=256 steps, MLP 18->32->32->14.
// 32x32x16 MFMA, mixed-precision split-bf16 (R17 term coverage).
// R18 vs R17 (572us): PERMUTED-K WEIGHT LAYOUT. MFMA contraction is
// invariant under a common permutation of A/B k-indices, so the next
// layer's weight rows are loaded (at init) in the exact order the previous
// layer's D-layout hands back: D regs 0-7 = rows {0-3,8-11}+4h, regs 8-15 =
// rows {16-19,24-27}+4h. Layer boundaries become 8 packbf ONLY (no xswap,
// no cndmask). L1's x-frag maps each lane's own ph/lat regs to its k-slots;
// only lat dims 8-11 cross halves -> 2 xswaps (was 4). Same 12 MFMAs.

#define BB 65536
#define TT 256
#define LL 14
#define HH 32
#define RSTRIDE 116   // LDS row stride in floats

typedef float f32x16 __attribute__((ext_vector_type(16)));
typedef __bf16 bf16x8 __attribute__((ext_vector_type(8)));
typedef __bf16 bf16x2 __attribute__((ext_vector_type(2)));
typedef int i32x2 __attribute__((ext_vector_type(2)));

static __device__ __forceinline__ unsigned packbf(float a, float b) {
    bf16x2 p;
    p[0] = (__bf16)a;
    p[1] = (__bf16)b;
    return __builtin_bit_cast(unsigned, p);
}

static __device__ __forceinline__ void split2(float v0, float v1,
                                              unsigned& hw, unsigned& lw) {
    const __bf16 h0 = (__bf16)v0, h1 = (__bf16)v1;
    hw = packbf(v0, v1);
    const float l0 = v0 - (float)h0;
    const float l1 = v1 - (float)h1;
    lw = packbf(l0, l1);
}

static __device__ __forceinline__ bf16x8 mkfrag(unsigned w0, unsigned w1,
                                                unsigned w2, unsigned w3) {
    union { unsigned u[4]; bf16x8 v; } x;
    x.u[0] = w0; x.u[1] = w1; x.u[2] = w2; x.u[3] = w3;
    return x.v;
}

static __device__ __forceinline__ f32x16 mf(bf16x8 a, bf16x8 b, f32x16 c) {
    return __builtin_amdgcn_mfma_f32_32x32x16_bf16(a, b, c, 0, 0, 0);
}

// a_out: hi lanes receive b from lane-32; lo lanes keep a.
#if __has_builtin(__builtin_amdgcn_permlane32_swap)
static __device__ __forceinline__ unsigned xswap1(unsigned a, unsigned b) {
    i32x2 r = __builtin_amdgcn_permlane32_swap((int)a, (int)b, false, false);
    return (unsigned)r[0];
}
#else
static __device__ __forceinline__ unsigned xswap1(unsigned a, unsigned b) {
    const int lane = threadIdx.x & 63;
    const int idx = (lane ^ 32) << 2;
    unsigned sb = (unsigned)__builtin_amdgcn_ds_bpermute(idx, (int)b);
    return (lane >= 32) ? sb : a;
}
#endif

// D-layout -> next-layer B-frags: just pack adjacent reg pairs (the weight
// rows of the next layer are pre-permuted to match).
static __device__ __forceinline__ void dfrag(const f32x16& h,
                                             bf16x8& B0, bf16x8& B1) {
    B0 = mkfrag(packbf(h[0], h[1]),  packbf(h[2], h[3]),
                packbf(h[4], h[5]),  packbf(h[6], h[7]));
    B1 = mkfrag(packbf(h[8], h[9]),  packbf(h[10], h[11]),
                packbf(h[12], h[13]), packbf(h[14], h[15]));
}

__global__ __launch_bounds__(256, 2)
void emulator_kernel(const float* __restrict__ phys,
                     const float* __restrict__ latents,
                     const float* __restrict__ W1g,
                     const float* __restrict__ b1g,
                     const float* __restrict__ W2g,
                     const float* __restrict__ b2g,
                     const float* __restrict__ W3g,
                     const float* __restrict__ b3g,
                     float* __restrict__ out) {
    __shared__ float lds[4 * 32 * RSTRIDE];

    const int tid = threadIdx.x;
    const int lane = tid & 63;
    const int wv = tid >> 6;
    const int c = lane & 31;
    const bool hi = lane >= 32;
    const int r = blockIdx.x * 128 + wv * 32 + c;

    // ---- W1 A-frags (k-slot -> x-dim mapping chosen to match lane-local
    //      residency of [ph, lat]):
    //  tile0: h0 j0-7 = x{ph0-3, lat0-3} = W1 rows 0-7
    //         h1 j0-7 = x{lat4-7, lat12,13, -, -} = W1 rows 8-11,16,17,0,0
    //  tile1: h0 j0-3 = lat8-11-hi (W1hi rows 12-15); j4-7 = lat8-11-lo (W1hi)
    //         h1 j0-3 = lat8-11-hi xswapped (W1lo rows 12-15); j4-7 = 0
    bf16x8 A1t0h, A1t0l, A1T1;
    {
        unsigned s0h, s0l, s1h, s1l, s2h, s2l, s3h, s3l;
        split2(W1g[(hi ? 8 : 0) * HH + c],  W1g[(hi ? 9 : 1) * HH + c],  s0h, s0l);
        split2(W1g[(hi ? 10 : 2) * HH + c], W1g[(hi ? 11 : 3) * HH + c], s1h, s1l);
        split2(W1g[(hi ? 16 : 4) * HH + c], W1g[(hi ? 17 : 5) * HH + c], s2h, s2l);
        unsigned s3h0, s3l0;
        split2(W1g[6 * HH + c], W1g[7 * HH + c], s3h0, s3l0);
        s3h = hi ? 0u : s3h0;
        s3l = hi ? 0u : s3l0;
        A1t0h = mkfrag(s0h, s1h, s2h, s3h);
        A1t0l = mkfrag(s0l, s1l, s2l, s3l);
        unsigned h12, l12, h14, l14;
        split2(W1g[12 * HH + c], W1g[13 * HH + c], h12, l12);
        split2(W1g[14 * HH + c], W1g[15 * HH + c], h14, l14);
        A1T1 = mkfrag(hi ? l12 : h12, hi ? l14 : h14,
                      hi ? 0u : h12,  hi ? 0u : h14);
    }

    // ---- W2 / W3 A-frags with PERMUTED row order:
    //  tile0 rows = {kb+0,kb+1,kb+2,kb+3, kb+8..kb+11}, kb = hi?4:0
    //  tile1 rows = +16
    const int kb = hi ? 4 : 0;
    bf16x8 A2h0, A2l0, A2h1, A2l1, A3h0, A3l0, A3h1, A3l1;
    {
        unsigned s0h, s0l, s1h, s1l, s2h, s2l, s3h, s3l;
        split2(W2g[(kb + 0) * HH + c], W2g[(kb + 1) * HH + c], s0h, s0l);
        split2(W2g[(kb + 2) * HH + c], W2g[(kb + 3) * HH + c], s1h, s1l);
        split2(W2g[(kb + 8) * HH + c], W2g[(kb + 9) * HH + c], s2h, s2l);
        split2(W2g[(kb + 10) * HH + c], W2g[(kb + 11) * HH + c], s3h, s3l);
        A2h0 = mkfrag(s0h, s1h, s2h, s3h);
        A2l0 = mkfrag(s0l, s1l, s2l, s3l);
        split2(W2g[(16 + kb + 0) * HH + c], W2g[(16 + kb + 1) * HH + c], s0h, s0l);
        split2(W2g[(16 + kb + 2) * HH + c], W2g[(16 + kb + 3) * HH + c], s1h, s1l);
        split2(W2g[(16 + kb + 8) * HH + c], W2g[(16 + kb + 9) * HH + c], s2h, s2l);
        split2(W2g[(16 + kb + 10) * HH + c], W2g[(16 + kb + 11) * HH + c], s3h, s3l);
        A2h1 = mkfrag(s0h, s1h, s2h, s3h);
        A2l1 = mkfrag(s0l, s1l, s2l, s3l);
    }
    {
        unsigned s0h, s0l, s1h, s1l, s2h, s2l, s3h, s3l;
#define W3E(row) ((c < LL) ? W3g[(row) * LL + c] : 0.0f)
        split2(W3E(kb + 0), W3E(kb + 1), s0h, s0l);
        split2(W3E(kb + 2), W3E(kb + 3), s1h, s1l);
        split2(W3E(kb + 8), W3E(kb + 9), s2h, s2l);
        split2(W3E(kb + 10), W3E(kb + 11), s3h, s3l);
        A3h0 = mkfrag(s0h, s1h, s2h, s3h);
        A3l0 = mkfrag(s0l, s1l, s2l, s3l);
        split2(W3E(16 + kb + 0), W3E(16 + kb + 1), s0h, s0l);
        split2(W3E(16 + kb + 2), W3E(16 + kb + 3), s1h, s1l);
        split2(W3E(16 + kb + 8), W3E(16 + kb + 9), s2h, s2l);
        split2(W3E(16 + kb + 10), W3E(16 + kb + 11), s3h, s3l);
        A3h1 = mkfrag(s0h, s1h, s2h, s3h);
        A3l1 = mkfrag(s0l, s1l, s2l, s3l);
#undef W3E
    }

    // ---- bias C-frags (D-layout) + zero C-frag -> pinned in AGPRs ----
    f32x16 cb1, cb2, cb3, z;
#pragma unroll
    for (int rr = 0; rr < 16; ++rr) {
        const int row = (rr & 3) + 8 * (rr >> 2) + (hi ? 4 : 0);
        cb1[rr] = b1g[row];
        cb2[rr] = b2g[row];
        cb3[rr] = (row < LL) ? b3g[row] : 0.0f;
        z[rr] = 0.0f;
    }

    // ---- latent state in D-layout (regs 0-7 meaningful; 8-15 stay 0) ----
    f32x16 lat;
#pragma unroll
    for (int i = 0; i < 16; ++i) lat[i] = 0.0f;
    {
        const float* lrow = latents + (size_t)r * LL;
        const float2* p01 = reinterpret_cast<const float2*>(lrow + (hi ? 4 : 0));
        const float2 v0 = p01[0], v1 = p01[1];
        lat[0] = v0.x; lat[1] = v0.y; lat[2] = v1.x; lat[3] = v1.y;
        const float2 v2 = reinterpret_cast<const float2*>(lrow + (hi ? 12 : 8))[0];
        lat[4] = v2.x; lat[5] = v2.y;
        if (!hi) {
            const float2 v3 = reinterpret_cast<const float2*>(lrow + 10)[0];
            lat[6] = v3.x; lat[7] = v3.y;
        }
    }

    const float4* pv = reinterpret_cast<const float4*>(phys) + (size_t)r * TT;
    float4 ph = pv[0];
    float* outr = out + (size_t)r * TT * LL;

    float* wrow_base = lds + wv * 32 * RSTRIDE + c * RSTRIDE;
    const int halfsel = hi ? 1 : 0;
    const float4* fl_src = reinterpret_cast<const float4*>(
        lds + wv * 32 * RSTRIDE + c * RSTRIDE + halfsel * 56);

#pragma unroll 1
    for (int t = 0; t < TT; ++t) {
        asm volatile("" : "+v"(A1t0h), "+v"(A1t0l), "+v"(A1T1),
                          "+v"(A2h0), "+v"(A2l0), "+v"(A2h1), "+v"(A2l1),
                          "+v"(A3h0), "+v"(A3l0), "+v"(A3h1), "+v"(A3l1));
        asm volatile("" : "+a"(cb1), "+a"(cb2), "+a"(cb3), "+a"(z));

        const float4 phn = pv[(t < TT - 1) ? (t + 1) : t];

        // ---- L1 B-frags (lane-local + 2 xswaps for lat dims 8-11) ----
        unsigned X0h, X0l, X1h, X1l, X2h, X2l, X3h, X3l, P0h, P0l, P1h, P1l;
        split2(lat[0], lat[1], X0h, X0l);
        split2(lat[2], lat[3], X1h, X1l);
        split2(lat[4], lat[5], X2h, X2l);
        split2(lat[6], lat[7], X3h, X3l);
        split2(ph.x, ph.y, P0h, P0l);
        split2(ph.z, ph.w, P1h, P1l);
        const unsigned sw89 = xswap1(X2h, X2h);    // hi lanes: lo's dims 8,9-hi
        const unsigned sw1011 = xswap1(X3h, X3h);  // hi lanes: lo's dims 10,11-hi
        bf16x8 B0h = mkfrag(hi ? X0h : P0h, hi ? X1h : P1h,
                            hi ? X2h : X0h, hi ? 0u : X1h);
        bf16x8 B0l = mkfrag(hi ? X0l : P0l, hi ? X1l : P1l,
                            hi ? X2l : X0l, hi ? 0u : X1l);
        bf16x8 B1 = mkfrag(hi ? sw89 : X2h, hi ? sw1011 : X3h,
                           hi ? 0u : X2l,   hi ? 0u : X3l);

        // ---- L1: 3-chain (tile0) + 1 (tile1) ----
        __builtin_amdgcn_s_setprio(1);
        f32x16 accA = mf(A1t0l, B0h, mf(A1t0h, B0l, mf(A1t0h, B0h, cb1)));
        f32x16 accB = mf(A1T1, B1, z);
        __builtin_amdgcn_s_setprio(0);
        f32x16 h1v;
#pragma unroll
        for (int i = 0; i < 16; ++i) h1v[i] = fmaxf(accA[i] + accB[i], 0.0f);

        // ---- L2: D-layout regs ARE the B-frags (permuted W2 rows) ----
        bf16x8 C0, C1;
        dfrag(h1v, C0, C1);
        __builtin_amdgcn_s_setprio(1);
        f32x16 a2A = mf(A2l0, C0, mf(A2h0, C0, cb2));
        f32x16 a2B = mf(A2l1, C1, mf(A2h1, C1, z));
        __builtin_amdgcn_s_setprio(0);
        f32x16 h2v;
#pragma unroll
        for (int i = 0; i < 16; ++i) h2v[i] = fmaxf(a2A[i] + a2B[i], 0.0f);

        // ---- L3 + residual ----
        bf16x8 D0, D1;
        dfrag(h2v, D0, D1);
        __builtin_amdgcn_s_setprio(1);
        f32x16 nlA = mf(A3l0, D0, mf(A3h0, D0, lat));
        f32x16 nlB = mf(A3l1, D1, mf(A3h1, D1, cb3));
        __builtin_amdgcn_s_setprio(0);
#pragma unroll
        for (int i = 0; i < 8; ++i) lat[i] = nlA[i] + nlB[i];
        // lat[8..15] remain 0 (W3 zero-padded rows; cb3 zero there)

        // ---- stage this step's 14 outputs into wave-private LDS ----
        {
            float* wr = wrow_base + (t & 7) * LL;
            if (!hi) {
                *reinterpret_cast<float2*>(wr + 0)  = make_float2(lat[0], lat[1]);
                *reinterpret_cast<float2*>(wr + 2)  = make_float2(lat[2], lat[3]);
                *reinterpret_cast<float2*>(wr + 8)  = make_float2(lat[4], lat[5]);
                *reinterpret_cast<float2*>(wr + 10) = make_float2(lat[6], lat[7]);
            } else {
                *reinterpret_cast<float2*>(wr + 4)  = make_float2(lat[0], lat[1]);
                *reinterpret_cast<float2*>(wr + 6)  = make_float2(lat[2], lat[3]);
                *reinterpret_cast<float2*>(wr + 12) = make_float2(lat[4], lat[5]);
            }
        }

        // ---- flush every 8 steps: 224B contiguous per lane ----
        if ((t & 7) == 7) {
            float4* gdst = reinterpret_cast<float4*>(
                outr + (size_t)(t - 7 + 4 * halfsel) * LL);
#pragma unroll
            for (int q = 0; q < 14; ++q) gdst[q] = fl_src[q];
        }

        ph = phn;
    }
}

extern "C" void kernel_launch(void* const* d_in, const int* in_sizes, int n_in,
                              void* d_out, int out_size, void* d_ws, size_t ws_size,
                              hipStream_t stream) {
    const float* phys    = (const float*)d_in[0];
    const float* latents = (const float*)d_in[1];
    const float* W1      = (const float*)d_in[2];
    const float* b1      = (const float*)d_in[3];
    const float* W2      = (const float*)d_in[4];
    const float* b2      = (const float*)d_in[5];
    const float* W3      = (const float*)d_in[6];
    const float* b3      = (const float*)d_in[7];
    float* out = (float*)d_out;

    const int threads = 256;             // 4 waves x 32 rows = 128 rows/block
    const int blocks = BB / 128;         // 512 blocks -> 2 waves/SIMD
    emulator_kernel<<<blocks, threads, 0, stream>>>(
        phys, latents, W1, b1, W2, b2, W3, b3, out);
}

// Round 19
// 567.324 us; speedup vs baseline: 7.0498x; 1.0015x over previous
//
#include <hip/hip_runtime.h>

// Recurrent MLP emulator: B=65536 rows, T=256 steps, MLP 18->32->32->14.
// 32x32x16 MFMA, mixed-precision split-bf16 (R17 term coverage).
// R19 vs R18 (568us, absmax bit-identical -> mapping verified):
//  UNIFORM-B L1. Every lane's B words are its OWN registers (same expression
//  both halves); ALL half-dependence moved into init-time A row selection:
//   tile0: B0=[ph01,ph23,latreg01,latreg23]; lo k0-7=(ph,dims0-3),
//          hi k8-15=(ph-dup -> A=0, dims4-7). 3-chain = 3 terms for each.
//   tile1: B1=[X2h,X3h,X2l,X3l]; lo k0-7=dims8-11(hi,lo),
//          hi k8-15=dims12,13(hi,lo)+pads. A1a=Whi(both), A1b=Wlo(xhi only),
//          2-chain.
//  Removes ALL in-loop xswaps + cndmasks + dual-source frag assembly.
//  L1 4->5 MFMAs (+8cyc) for ~-40 VALU ops. Term coverage unchanged.

#define BB 65536
#define TT 256
#define LL 14
#define HH 32
#define RSTRIDE 116   // LDS row stride in floats

typedef float f32x16 __attribute__((ext_vector_type(16)));
typedef __bf16 bf16x8 __attribute__((ext_vector_type(8)));
typedef __bf16 bf16x2 __attribute__((ext_vector_type(2)));

static __device__ __forceinline__ unsigned packbf(float a, float b) {
    bf16x2 p;
    p[0] = (__bf16)a;
    p[1] = (__bf16)b;
    return __builtin_bit_cast(unsigned, p);
}

static __device__ __forceinline__ void split2(float v0, float v1,
                                              unsigned& hw, unsigned& lw) {
    const __bf16 h0 = (__bf16)v0, h1 = (__bf16)v1;
    hw = packbf(v0, v1);
    const float l0 = v0 - (float)h0;
    const float l1 = v1 - (float)h1;
    lw = packbf(l0, l1);
}

static __device__ __forceinline__ bf16x8 mkfrag(unsigned w0, unsigned w1,
                                                unsigned w2, unsigned w3) {
    union { unsigned u[4]; bf16x8 v; } x;
    x.u[0] = w0; x.u[1] = w1; x.u[2] = w2; x.u[3] = w3;
    return x.v;
}

static __device__ __forceinline__ f32x16 mf(bf16x8 a, bf16x8 b, f32x16 c) {
    return __builtin_amdgcn_mfma_f32_32x32x16_bf16(a, b, c, 0, 0, 0);
}

// D-layout -> next-layer B-frags: pack adjacent reg pairs (next layer's
// weight rows pre-permuted to match).
static __device__ __forceinline__ void dfrag(const f32x16& h,
                                             bf16x8& B0, bf16x8& B1) {
    B0 = mkfrag(packbf(h[0], h[1]),  packbf(h[2], h[3]),
                packbf(h[4], h[5]),  packbf(h[6], h[7]));
    B1 = mkfrag(packbf(h[8], h[9]),  packbf(h[10], h[11]),
                packbf(h[12], h[13]), packbf(h[14], h[15]));
}

__global__ __launch_bounds__(256, 2)
void emulator_kernel(const float* __restrict__ phys,
                     const float* __restrict__ latents,
                     const float* __restrict__ W1g,
                     const float* __restrict__ b1g,
                     const float* __restrict__ W2g,
                     const float* __restrict__ b2g,
                     const float* __restrict__ W3g,
                     const float* __restrict__ b3g,
                     float* __restrict__ out) {
    __shared__ float lds[4 * 32 * RSTRIDE];

    const int tid = threadIdx.x;
    const int lane = tid & 63;
    const int wv = tid >> 6;
    const int c = lane & 31;
    const bool hi = lane >= 32;
    const int r = blockIdx.x * 128 + wv * 32 + c;

    // ---- W1 A-frags (uniform-B design; all half-deps resolved HERE) ----
    // tile0: lo words = Whi/Wlo rows [01,23,45,67]; hi words = [0,0,rows89,rows10-11]
    // tile1a: lo = Whi rows[12-13,14-15,12-13,14-15]; hi = [Whi16-17,0,Whi16-17,0]
    // tile1b: lo = Wlo rows[12-13,14-15,0,0];         hi = [Wlo16-17,0,0,0]
    bf16x8 A0h, A0l, A1a, A1b;
    {
        unsigned s01h, s01l, s23h, s23l, s45h, s45l, s67h, s67l;
        split2(W1g[(hi ? 8 : 0) * HH + c], W1g[(hi ? 9 : 1) * HH + c], s45h, s45l);
        split2(W1g[(hi ? 10 : 2) * HH + c], W1g[(hi ? 11 : 3) * HH + c], s67h, s67l);
        if (!hi) {
            split2(W1g[0 * HH + c], W1g[1 * HH + c], s01h, s01l);
            split2(W1g[2 * HH + c], W1g[3 * HH + c], s23h, s23l);
            // remap: for lo, words are rows[01,23,45,67]
            unsigned t45h = s45h, t45l = s45l, t67h = s67h, t67l = s67l;
            // (s45 currently holds rows 0,1? No: for lo, first split2 used rows 0,1.)
            // For lo: first split2 read rows 0,1 -> that's s45 slot; fix below.
            A0h = mkfrag(t45h, t67h, 0, 0);  // placeholder, corrected after
            A0l = mkfrag(t45l, t67l, 0, 0);
            // Recompute cleanly for lo: words [rows01, rows23, rows45, rows67]
            unsigned a01h, a01l, a23h, a23l, a45h, a45l, a67h, a67l;
            split2(W1g[0 * HH + c], W1g[1 * HH + c], a01h, a01l);
            split2(W1g[2 * HH + c], W1g[3 * HH + c], a23h, a23l);
            split2(W1g[4 * HH + c], W1g[5 * HH + c], a45h, a45l);
            split2(W1g[6 * HH + c], W1g[7 * HH + c], a67h, a67l);
            A0h = mkfrag(a01h, a23h, a45h, a67h);
            A0l = mkfrag(a01l, a23l, a45l, a67l);
        } else {
            // hi: words = [0, 0, rows89, rows10-11]
            A0h = mkfrag(0, 0, s45h, s67h);
            A0l = mkfrag(0, 0, s45l, s67l);
        }
        unsigned h1213, l1213, h1415, l1415, h1617, l1617;
        split2(W1g[12 * HH + c], W1g[13 * HH + c], h1213, l1213);
        split2(W1g[14 * HH + c], W1g[15 * HH + c], h1415, l1415);
        split2(W1g[16 * HH + c], W1g[17 * HH + c], h1617, l1617);
        if (!hi) {
            A1a = mkfrag(h1213, h1415, h1213, h1415);
            A1b = mkfrag(l1213, l1415, 0, 0);
        } else {
            A1a = mkfrag(h1617, 0, h1617, 0);
            A1b = mkfrag(l1617, 0, 0, 0);
        }
    }

    // ---- W2 / W3 A-frags, permuted row order (matches D-layout) ----
    const int kb = hi ? 4 : 0;
    bf16x8 A2h0, A2l0, A2h1, A2l1, A3h0, A3l0, A3h1, A3l1;
    {
        unsigned s0h, s0l, s1h, s1l, s2h, s2l, s3h, s3l;
        split2(W2g[(kb + 0) * HH + c], W2g[(kb + 1) * HH + c], s0h, s0l);
        split2(W2g[(kb + 2) * HH + c], W2g[(kb + 3) * HH + c], s1h, s1l);
        split2(W2g[(kb + 8) * HH + c], W2g[(kb + 9) * HH + c], s2h, s2l);
        split2(W2g[(kb + 10) * HH + c], W2g[(kb + 11) * HH + c], s3h, s3l);
        A2h0 = mkfrag(s0h, s1h, s2h, s3h);
        A2l0 = mkfrag(s0l, s1l, s2l, s3l);
        split2(W2g[(16 + kb + 0) * HH + c], W2g[(16 + kb + 1) * HH + c], s0h, s0l);
        split2(W2g[(16 + kb + 2) * HH + c], W2g[(16 + kb + 3) * HH + c], s1h, s1l);
        split2(W2g[(16 + kb + 8) * HH + c], W2g[(16 + kb + 9) * HH + c], s2h, s2l);
        split2(W2g[(16 + kb + 10) * HH + c], W2g[(16 + kb + 11) * HH + c], s3h, s3l);
        A2h1 = mkfrag(s0h, s1h, s2h, s3h);
        A2l1 = mkfrag(s0l, s1l, s2l, s3l);
    }
    {
        unsigned s0h, s0l, s1h, s1l, s2h, s2l, s3h, s3l;
#define W3E(row) ((c < LL) ? W3g[(row) * LL + c] : 0.0f)
        split2(W3E(kb + 0), W3E(kb + 1), s0h, s0l);
        split2(W3E(kb + 2), W3E(kb + 3), s1h, s1l);
        split2(W3E(kb + 8), W3E(kb + 9), s2h, s2l);
        split2(W3E(kb + 10), W3E(kb + 11), s3h, s3l);
        A3h0 = mkfrag(s0h, s1h, s2h, s3h);
        A3l0 = mkfrag(s0l, s1l, s2l, s3l);
        split2(W3E(16 + kb + 0), W3E(16 + kb + 1), s0h, s0l);
        split2(W3E(16 + kb + 2), W3E(16 + kb + 3), s1h, s1l);
        split2(W3E(16 + kb + 8), W3E(16 + kb + 9), s2h, s2l);
        split2(W3E(16 + kb + 10), W3E(16 + kb + 11), s3h, s3l);
        A3h1 = mkfrag(s0h, s1h, s2h, s3h);
        A3l1 = mkfrag(s0l, s1l, s2l, s3l);
#undef W3E
    }

    // ---- bias C-frags (D-layout) + zero C-frag -> pinned in AGPRs ----
    f32x16 cb1, cb2, cb3, z;
#pragma unroll
    for (int rr = 0; rr < 16; ++rr) {
        const int row = (rr & 3) + 8 * (rr >> 2) + (hi ? 4 : 0);
        cb1[rr] = b1g[row];
        cb2[rr] = b2g[row];
        cb3[rr] = (row < LL) ? b3g[row] : 0.0f;
        z[rr] = 0.0f;
    }

    // ---- latent state in D-layout (regs 0-7 meaningful; 8-15 stay 0) ----
    f32x16 lat;
#pragma unroll
    for (int i = 0; i < 16; ++i) lat[i] = 0.0f;
    {
        const float* lrow = latents + (size_t)r * LL;
        const float2* p01 = reinterpret_cast<const float2*>(lrow + (hi ? 4 : 0));
        const float2 v0 = p01[0], v1 = p01[1];
        lat[0] = v0.x; lat[1] = v0.y; lat[2] = v1.x; lat[3] = v1.y;
        const float2 v2 = reinterpret_cast<const float2*>(lrow + (hi ? 12 : 8))[0];
        lat[4] = v2.x; lat[5] = v2.y;
        if (!hi) {
            const float2 v3 = reinterpret_cast<const float2*>(lrow + 10)[0];
            lat[6] = v3.x; lat[7] = v3.y;
        }
    }

    const float4* pv = reinterpret_cast<const float4*>(phys) + (size_t)r * TT;
    float4 ph = pv[0];
    float* outr = out + (size_t)r * TT * LL;

    float* wrow_base = lds + wv * 32 * RSTRIDE + c * RSTRIDE;
    const int halfsel = hi ? 1 : 0;
    const float4* fl_src = reinterpret_cast<const float4*>(
        lds + wv * 32 * RSTRIDE + c * RSTRIDE + halfsel * 56);

#pragma unroll 1
    for (int t = 0; t < TT; ++t) {
        asm volatile("" : "+v"(A0h), "+v"(A0l), "+v"(A1a), "+v"(A1b),
                          "+v"(A2h0), "+v"(A2l0), "+v"(A2h1), "+v"(A2l1),
                          "+v"(A3h0), "+v"(A3l0), "+v"(A3h1), "+v"(A3l1));
        asm volatile("" : "+a"(cb1), "+a"(cb2), "+a"(cb3), "+a"(z));

        const float4 phn = pv[(t < TT - 1) ? (t + 1) : t];

        // ---- L1 B-frags: every lane packs its OWN registers (no selects) ----
        unsigned X0h, X0l, X1h, X1l, X2h, X2l, X3h, X3l, P0h, P0l, P1h, P1l;
        split2(lat[0], lat[1], X0h, X0l);
        split2(lat[2], lat[3], X1h, X1l);
        split2(lat[4], lat[5], X2h, X2l);
        split2(lat[6], lat[7], X3h, X3l);
        split2(ph.x, ph.y, P0h, P0l);
        split2(ph.z, ph.w, P1h, P1l);
        bf16x8 B0h = mkfrag(P0h, P1h, X0h, X1h);
        bf16x8 B0l = mkfrag(P0l, P1l, X0l, X1l);
        bf16x8 B1 = mkfrag(X2h, X3h, X2l, X3l);

        // ---- L1: tile0 3-chain + tile1 2-chain (5 MFMAs) ----
        __builtin_amdgcn_s_setprio(1);
        f32x16 accA = mf(A0l, B0h, mf(A0h, B0l, mf(A0h, B0h, cb1)));
        f32x16 accB = mf(A1b, B1, mf(A1a, B1, z));
        __builtin_amdgcn_s_setprio(0);
        f32x16 h1v;
#pragma unroll
        for (int i = 0; i < 16; ++i) h1v[i] = fmaxf(accA[i] + accB[i], 0.0f);

        // ---- L2: D-layout regs ARE the B-frags ----
        bf16x8 C0, C1;
        dfrag(h1v, C0, C1);
        __builtin_amdgcn_s_setprio(1);
        f32x16 a2A = mf(A2l0, C0, mf(A2h0, C0, cb2));
        f32x16 a2B = mf(A2l1, C1, mf(A2h1, C1, z));
        __builtin_amdgcn_s_setprio(0);
        f32x16 h2v;
#pragma unroll
        for (int i = 0; i < 16; ++i) h2v[i] = fmaxf(a2A[i] + a2B[i], 0.0f);

        // ---- L3 + residual ----
        bf16x8 D0, D1;
        dfrag(h2v, D0, D1);
        __builtin_amdgcn_s_setprio(1);
        f32x16 nlA = mf(A3l0, D0, mf(A3h0, D0, lat));
        f32x16 nlB = mf(A3l1, D1, mf(A3h1, D1, cb3));
        __builtin_amdgcn_s_setprio(0);
#pragma unroll
        for (int i = 0; i < 8; ++i) lat[i] = nlA[i] + nlB[i];
        // lat[8..15] remain 0 (W3 zero-padded rows; cb3 zero there)

        // ---- stage this step's 14 outputs into wave-private LDS ----
        {
            float* wr = wrow_base + (t & 7) * LL;
            if (!hi) {
                *reinterpret_cast<float2*>(wr + 0)  = make_float2(lat[0], lat[1]);
                *reinterpret_cast<float2*>(wr + 2)  = make_float2(lat[2], lat[3]);
                *reinterpret_cast<float2*>(wr + 8)  = make_float2(lat[4], lat[5]);
                *reinterpret_cast<float2*>(wr + 10) = make_float2(lat[6], lat[7]);
            } else {
                *reinterpret_cast<float2*>(wr + 4)  = make_float2(lat[0], lat[1]);
                *reinterpret_cast<float2*>(wr + 6)  = make_float2(lat[2], lat[3]);
                *reinterpret_cast<float2*>(wr + 12) = make_float2(lat[4], lat[5]);
            }
        }

        // ---- flush every 8 steps: 224B contiguous per lane ----
        if ((t & 7) == 7) {
            float4* gdst = reinterpret_cast<float4*>(
                outr + (size_t)(t - 7 + 4 * halfsel) * LL);
#pragma unroll
            for (int q = 0; q < 14; ++q) gdst[q] = fl_src[q];
        }

        ph = phn;
    }
}

extern "C" void kernel_launch(void* const* d_in, const int* in_sizes, int n_in,
                              void* d_out, int out_size, void* d_ws, size_t ws_size,
                              hipStream_t stream) {
    const float* phys    = (const float*)d_in[0];
    const float* latents = (const float*)d_in[1];
    const float* W1      = (const float*)d_in[2];
    const float* b1      = (const float*)d_in[3];
    const float* W2      = (const float*)d_in[4];
    const float* b2      = (const float*)d_in[5];
    const float* W3      = (const float*)d_in[6];
    const float* b3      = (const float*)d_in[7];
    float* out = (float*)d_out;

    const int threads = 256;             // 4 waves x 32 rows = 128 rows/block
    const int blocks = BB / 128;         // 512 blocks -> 2 waves/SIMD
    emulator_kernel<<<blocks, threads, 0, stream>>>(
        phys, latents, W1, b1, W2, b2, W3, b3, out);
}